// Round 9
// baseline (4861.514 us; speedup 1.0000x reference)
//
#include <hip/hip_runtime.h>
#include <hip/hip_bf16.h>

typedef __bf16 bf16_t;
typedef __bf16 bf16x8 __attribute__((ext_vector_type(8)));
typedef float f32x4 __attribute__((ext_vector_type(4)));

#define GLOAD16(gp, lp) __builtin_amdgcn_global_load_lds(                      \
    (const __attribute__((address_space(1))) void*)(gp),                       \
    (__attribute__((address_space(3))) void*)(lp), 16, 0, 0)
#define BARRIER() asm volatile("s_barrier" ::: "memory")
#define VMC(n) asm volatile("s_waitcnt vmcnt(" #n ")" ::: "memory")
#define LGK0()                                                                 \
  do {                                                                         \
    asm volatile("s_waitcnt lgkmcnt(0)" ::: "memory");                         \
    __builtin_amdgcn_sched_barrier(0);                                         \
  } while (0)

// ---------------- cast fp32 -> bf16 (vectorized x8) ----------------
__global__ __launch_bounds__(256) void cast_f32_bf16_k(
    const float* __restrict__ in, bf16_t* __restrict__ out, long n8) {
  long i = (long)blockIdx.x * blockDim.x + threadIdx.x;
  long stride = (long)gridDim.x * blockDim.x;
  for (; i < n8; i += stride) {
    long e = i * 8;
    float4 a = *(const float4*)(in + e);
    float4 b = *(const float4*)(in + e + 4);
    bf16x8 o;
    o[0] = (__bf16)a.x; o[1] = (__bf16)a.y; o[2] = (__bf16)a.z; o[3] = (__bf16)a.w;
    o[4] = (__bf16)b.x; o[5] = (__bf16)b.y; o[6] = (__bf16)b.z; o[7] = (__bf16)b.w;
    *(bf16x8*)(out + e) = o;
  }
}

// ============ 256x256-tile 8-wave GEMM, BK=32, 2x32KB LDS double-buffer ====
// 64KB LDS/block -> 2 blocks/CU: two independent barrier domains anti-phase,
// so one block's DS bursts hide under the other's MFMA clusters (m114).
// Per K-step: VMC(0)+barrier, stage next tile, 2 phases {ds_read, lgkm(0),
// 16 MFMA}. LDS rows 64B; 16B slot ^= (row>>1)&3; staging inverse-swizzles
// the global source (linear LDS dest for global_load_lds). Frag regs: 48.
template <int BIAS, bool MUL>
__global__ __launch_bounds__(512, 4) void gemm256(
    const bf16_t* __restrict__ A, const bf16_t* __restrict__ B,
    const float* __restrict__ bias, const bf16_t* __restrict__ mulm,
    bf16_t* __restrict__ out, int M, int N, int K) {
  __shared__ __align__(1024) char lds[65536];
  const int tid = threadIdx.x;
  const int gx = N >> 8;
  int bid = blockIdx.y * gx + blockIdx.x;
  const int nwg = gridDim.x * gridDim.y;  // multiple of 8 for our shapes
  const int cpx = nwg >> 3;
  bid = (bid & 7) * cpx + (bid >> 3);     // XCD-aware bijective swizzle
  const long row0 = (long)(bid / gx) * 256;
  const long col0 = (long)(bid % gx) * 256;

  const int w = tid >> 6, lane = tid & 63;
  const int wm = w >> 2, wn = w & 3;      // 2M x 4N waves
  const int fr = lane & 15, fq = lane >> 4;
  const int sx = (fr >> 1) & 3;           // read-side swizzle (lane-const)

  // fragment byte offsets within one 32KB buffer (A at 0, B at 16384)
  int aoff[8], boff[4];
#pragma unroll
  for (int i = 0; i < 8; ++i)
    aoff[i] = (wm * 128 + i * 16 + fr) * 64 + ((fq ^ sx) << 4);
#pragma unroll
  for (int j = 0; j < 4; ++j)
    boff[j] = 16384 + (wn * 64 + j * 16 + fr) * 64 + ((fq ^ sx) << 4);

  // staging: linear LDS dest; inverse-swizzled global k-chunk per phys slot
  const int p0 = w * 1024 + lane * 16;
  const int p1 = p0 + 8192;
  const int r0 = p0 >> 6, r1 = p1 >> 6;
  const int s0 = ((p0 >> 4) & 3) ^ ((r0 >> 1) & 3);
  const int s1 = ((p1 >> 4) & 3) ^ ((r1 >> 1) & 3);
  const bf16_t* As0 = A + (row0 + r0) * (long)K + (s0 << 3);
  const bf16_t* As1 = A + (row0 + r1) * (long)K + (s1 << 3);
  const bf16_t* Bs0 = B + (col0 + r0) * (long)K + (s0 << 3);
  const bf16_t* Bs1 = B + (col0 + r1) * (long)K + (s1 << 3);
  const int dst0 = w * 1024;
  const int dst1 = dst0 + 8192;

  f32x4 acc[8][4] = {};
  bf16x8 a0[4], a1[4], bv[4];
  const int NT = K >> 5;  // >= 2

  // prologue: stage tile 0 into buf0
  GLOAD16(As0, lds + dst0);
  GLOAD16(As1, lds + dst1);
  GLOAD16(Bs0, lds + 16384 + dst0);
  GLOAD16(Bs1, lds + 16384 + dst1);

  for (int T = 0; T < NT; ++T) {
    char* buf = lds + (T & 1) * 32768;
    char* nb = lds + ((T + 1) & 1) * 32768;
    // tile T staged (all waves) -> rendezvous; then stage T+1 into buf^1
    VMC(0);
    BARRIER();
    if (T < NT - 1) {
      GLOAD16(As0 + (long)(T + 1) * 32, nb + dst0);
      GLOAD16(As1 + (long)(T + 1) * 32, nb + dst1);
      GLOAD16(Bs0 + (long)(T + 1) * 32, nb + 16384 + dst0);
      GLOAD16(Bs1 + (long)(T + 1) * 32, nb + 16384 + dst1);
    }
    // phase 1: A rows 0..3 + B
#pragma unroll
    for (int i = 0; i < 4; ++i) a0[i] = *(const bf16x8*)(buf + aoff[i]);
#pragma unroll
    for (int j = 0; j < 4; ++j) bv[j] = *(const bf16x8*)(buf + boff[j]);
    LGK0();
    __builtin_amdgcn_s_setprio(1);
#pragma unroll
    for (int i = 0; i < 4; ++i)
#pragma unroll
      for (int j = 0; j < 4; ++j)
        acc[i][j] = __builtin_amdgcn_mfma_f32_16x16x32_bf16(a0[i], bv[j],
                                                            acc[i][j], 0, 0, 0);
    __builtin_amdgcn_s_setprio(0);
    // phase 2: A rows 4..7
#pragma unroll
    for (int i = 0; i < 4; ++i) a1[i] = *(const bf16x8*)(buf + aoff[4 + i]);
    LGK0();
    __builtin_amdgcn_s_setprio(1);
#pragma unroll
    for (int i = 0; i < 4; ++i)
#pragma unroll
      for (int j = 0; j < 4; ++j)
        acc[4 + i][j] = __builtin_amdgcn_mfma_f32_16x16x32_bf16(
            a1[i], bv[j], acc[4 + i][j], 0, 0, 0);
    __builtin_amdgcn_s_setprio(0);
  }

  // epilogue: C/D layout col=lane&15, row=(lane>>4)*4+r
#pragma unroll
  for (int i = 0; i < 8; ++i)
#pragma unroll
    for (int j = 0; j < 4; ++j)
#pragma unroll
      for (int r = 0; r < 4; ++r) {
        long gi = row0 + wm * 128 + i * 16 + fq * 4 + r;
        long gj = col0 + wn * 64 + j * 16 + fr;
        float v = acc[i][j][r];
        if (BIAS == 1) v += bias[gj];
        long idx = gi * (long)N + gj;
        if (MUL) v *= (float)mulm[idx];
        out[idx] = (bf16_t)v;
      }
}

// ---------------- NT GEMM (m97 128x128), slot-swizzled, XCD-grouped --------
// GROUP 0: blocks sharing an A row-tile grouped on one XCD (requires gy%8==0)
// GROUP 1: blocks sharing a B col-tile grouped on one XCD (requires gx%8==0)
template <int BIAS, bool MUL, bool RES, bool OUTBF16, int GROUP>
__global__ __launch_bounds__(256) void gemm_nt(
    const bf16_t* __restrict__ A, const bf16_t* __restrict__ B,
    const float* __restrict__ bias, const bf16_t* __restrict__ mulm,
    const float* __restrict__ res, float* __restrict__ outf,
    bf16_t* __restrict__ outb, int M, int N, int K) {
  __shared__ bf16_t As[128 * 32];
  __shared__ bf16_t Bs[128 * 32];
  const int tid = threadIdx.x;
  const int gx = gridDim.x, gy = gridDim.y;
  const int n = blockIdx.y * gx + blockIdx.x;
  const int xcd = n & 7, q = n >> 3;
  int br, bc;
  if (GROUP == 0) { br = xcd + 8 * (q / gx); bc = q % gx; }
  else            { bc = xcd + 8 * (q / gy); br = q % gy; }
  const long row0 = (long)br * 128;
  const long col0 = (long)bc * 128;
  const int wid = tid >> 6, lane = tid & 63;
  const int wr = (wid >> 1) * 64;
  const int wc = (wid & 1) * 64;
  const int fr = lane & 15, fq = lane >> 4;
  const int sx = (fr >> 1) & 3;
  const int srow = tid >> 2;
  const int scol = ((tid & 3) ^ ((srow >> 1) & 3)) * 8;  // inverse-swz source

  f32x4 acc[4][4] = {};

  const bf16_t* Ag = A + (row0 + srow) * (long)K + scol;
  const bf16_t* Bg = B + (col0 + srow) * (long)K + scol;
  const long k64 = 64L * K;
  bf16_t* ldsA = As + wid * 512;
  bf16_t* ldsB = Bs + wid * 512;

  for (int k0 = 0; k0 < K; k0 += 32) {
    GLOAD16(Ag + k0, ldsA);
    GLOAD16(Ag + k0 + k64, ldsA + 2048);
    GLOAD16(Bg + k0, ldsB);
    GLOAD16(Bg + k0 + k64, ldsB + 2048);
    __syncthreads();
    bf16x8 av[4], bv[4];
#pragma unroll
    for (int i = 0; i < 4; i++)
      av[i] = *(const bf16x8*)(As + (wr + i * 16 + fr) * 32 + ((fq ^ sx) << 3));
#pragma unroll
    for (int j = 0; j < 4; j++)
      bv[j] = *(const bf16x8*)(Bs + (wc + j * 16 + fr) * 32 + ((fq ^ sx) << 3));
#pragma unroll
    for (int i = 0; i < 4; i++)
#pragma unroll
      for (int j = 0; j < 4; j++)
        acc[i][j] = __builtin_amdgcn_mfma_f32_16x16x32_bf16(av[i], bv[j],
                                                            acc[i][j], 0, 0, 0);
    __syncthreads();
  }

#pragma unroll
  for (int i = 0; i < 4; i++) {
#pragma unroll
    for (int j = 0; j < 4; j++) {
#pragma unroll
      for (int r = 0; r < 4; r++) {
        long gi = row0 + wr + i * 16 + fq * 4 + r;
        long gj = col0 + wc + j * 16 + fr;
        float v = acc[i][j][r];
        if (BIAS == 1) v += bias[gj];
        if (BIAS == 2) v += bias[gi];
        long idx = gi * (long)N + gj;
        if (MUL) v *= (float)mulm[idx];
        if (RES) v += res[idx];
        if (OUTBF16) outb[idx] = (bf16_t)v;
        else outf[idx] = v;
      }
    }
  }
}

// ---------------- row softmax over 8192 cols, bf16 in-place ----------------
__global__ __launch_bounds__(256) void softmax_bf16_inplace(
    bf16_t* __restrict__ buf) {
  const long row = blockIdx.x;
  bf16_t* p = buf + row * 8192;
  const int t = threadIdx.x;
  float v[32];
#pragma unroll
  for (int i = 0; i < 4; i++) {
    bf16x8 raw = *(const bf16x8*)(p + t * 32 + i * 8);
#pragma unroll
    for (int j = 0; j < 8; j++) v[i * 8 + j] = (float)raw[j];
  }
  float m = -1e30f;
#pragma unroll
  for (int i = 0; i < 32; i++) m = fmaxf(m, v[i]);
  for (int off = 32; off; off >>= 1) m = fmaxf(m, __shfl_xor(m, off, 64));
  __shared__ float redm[4], reds[4];
  if ((t & 63) == 0) redm[t >> 6] = m;
  __syncthreads();
  m = fmaxf(fmaxf(redm[0], redm[1]), fmaxf(redm[2], redm[3]));
  float s = 0.f;
#pragma unroll
  for (int i = 0; i < 32; i++) {
    v[i] = __expf(v[i] - m);
    s += v[i];
  }
  for (int off = 32; off; off >>= 1) s += __shfl_xor(s, off, 64);
  if ((t & 63) == 0) reds[t >> 6] = s;
  __syncthreads();
  s = reds[0] + reds[1] + reds[2] + reds[3];
  float inv = 1.0f / s;
#pragma unroll
  for (int i = 0; i < 4; i++) {
    bf16x8 o;
#pragma unroll
    for (int j = 0; j < 8; j++) o[j] = (bf16_t)(v[i * 8 + j] * inv);
    *(bf16x8*)(p + t * 32 + i * 8) = o;
  }
}

// --------- row softmax: bf16 logits in, fp32 out + bf16 in-place ----------
__global__ __launch_bounds__(256) void softmax_f_k(bf16_t* __restrict__ fm,
                                                   float* __restrict__ outf) {
  const long row = blockIdx.x;
  bf16_t* p = fm + row * 8192;
  float* q = outf + row * 8192;
  const int t = threadIdx.x;
  float v[32];
#pragma unroll
  for (int i = 0; i < 4; i++) {
    bf16x8 raw = *(const bf16x8*)(p + t * 32 + i * 8);
#pragma unroll
    for (int j = 0; j < 8; j++) v[i * 8 + j] = (float)raw[j];
  }
  float m = -1e30f;
#pragma unroll
  for (int i = 0; i < 32; i++) m = fmaxf(m, v[i]);
  for (int off = 32; off; off >>= 1) m = fmaxf(m, __shfl_xor(m, off, 64));
  __shared__ float redm[4], reds[4];
  if ((t & 63) == 0) redm[t >> 6] = m;
  __syncthreads();
  m = fmaxf(fmaxf(redm[0], redm[1]), fmaxf(redm[2], redm[3]));
  float s = 0.f;
#pragma unroll
  for (int i = 0; i < 32; i++) {
    v[i] = __expf(v[i] - m);
    s += v[i];
  }
  for (int off = 32; off; off >>= 1) s += __shfl_xor(s, off, 64);
  if ((t & 63) == 0) reds[t >> 6] = s;
  __syncthreads();
  s = reds[0] + reds[1] + reds[2] + reds[3];
  float inv = 1.0f / s;
#pragma unroll
  for (int i = 0; i < 8; i++) {
    float4 o;
    o.x = v[i * 4 + 0] * inv;
    o.y = v[i * 4 + 1] * inv;
    o.z = v[i * 4 + 2] * inv;
    o.w = v[i * 4 + 3] * inv;
    *(float4*)(q + t * 32 + i * 4) = o;
  }
#pragma unroll
  for (int i = 0; i < 4; i++) {
    bf16x8 o;
#pragma unroll
    for (int j = 0; j < 8; j++) o[j] = (bf16_t)(v[i * 8 + j] * inv);
    *(bf16x8*)(p + t * 32 + i * 8) = o;
  }
}

// ---------------------------------------------------------------------------
extern "C" void kernel_launch(void* const* d_in, const int* in_sizes, int n_in,
                              void* d_out, int out_size, void* d_ws,
                              size_t ws_size, hipStream_t stream) {
  const int N = 8192, C = 2048, IC = 1024;
  const float* x = (const float*)d_in[0];
  const float* theta_w = (const float*)d_in[1];
  const float* theta_b = (const float*)d_in[2];
  const float* phi_w = (const float*)d_in[3];
  const float* phi_b = (const float*)d_in[4];
  const float* g_w = (const float*)d_in[5];
  const float* g_b = (const float*)d_in[6];
  const float* W_w = (const float*)d_in[7];
  const float* W_b = (const float*)d_in[8];
  const float* mask_w = (const float*)d_in[9];
  const float* mask_b = (const float*)d_in[10];

  float* z_out = (float*)d_out;            // [N,C] fp32
  float* f_out = z_out + (long)N * C;      // [N,N] fp32

  // d_out-hosted scratch (dead before those regions' final writes):
  bf16_t* ML = (bf16_t*)f_out;             // [N,N] bf16 mask logits -> mask
  bf16_t* th16 = (bf16_t*)z_out;           // [N,IC]
  bf16_t* ph16 = th16 + (long)N * IC;      // [N,IC]
  bf16_t* gT16 = ph16 + (long)N * IC;      // [IC,N]

  char* w = (char*)d_ws;
  bf16_t* xb = (bf16_t*)w;      w += (long)N * C * 2;
  bf16_t* mwb = (bf16_t*)w;     w += (long)N * C * 2;
  bf16_t* thwb = (bf16_t*)w;    w += (long)IC * C * 2;
  bf16_t* phwb = (bf16_t*)w;    w += (long)IC * C * 2;
  bf16_t* gwb = (bf16_t*)w;     w += (long)IC * C * 2;
  bf16_t* Wwb = (bf16_t*)w;     w += (long)C * IC * 2;
  bf16_t* fm = (bf16_t*)w;      w += (long)N * N * 2;   // f*mask logits -> P
  bf16_t* y16 = (bf16_t*)w;     w += (long)N * IC * 2;

  cast_f32_bf16_k<<<8192, 256, 0, stream>>>(x, xb, (long)N * C / 8);
  cast_f32_bf16_k<<<8192, 256, 0, stream>>>(mask_w, mwb, (long)N * C / 8);
  cast_f32_bf16_k<<<1024, 256, 0, stream>>>(theta_w, thwb, (long)IC * C / 8);
  cast_f32_bf16_k<<<1024, 256, 0, stream>>>(phi_w, phwb, (long)IC * C / 8);
  cast_f32_bf16_k<<<1024, 256, 0, stream>>>(g_w, gwb, (long)IC * C / 8);
  cast_f32_bf16_k<<<1024, 256, 0, stream>>>(W_w, Wwb, (long)C * IC / 8);

  // projections (128^2 kernel, XCD-grouped)
  gemm_nt<1, false, false, true, 0><<<dim3(IC / 128, N / 128), 256, 0, stream>>>(
      xb, thwb, theta_b, nullptr, nullptr, nullptr, th16, N, IC, C);
  gemm_nt<1, false, false, true, 0><<<dim3(IC / 128, N / 128), 256, 0, stream>>>(
      xb, phwb, phi_b, nullptr, nullptr, nullptr, ph16, N, IC, C);
  gemm_nt<2, false, false, true, 1><<<dim3(N / 128, IC / 128), 256, 0, stream>>>(
      gwb, xb, g_b, nullptr, nullptr, nullptr, gT16, IC, N, C);
  // mask logits (256^2 2-blocks/CU kernel), bias per col
  gemm256<1, false><<<dim3(N / 256, N / 256), 512, 0, stream>>>(
      xb, mwb, mask_b, nullptr, ML, N, N, C);
  softmax_bf16_inplace<<<N, 256, 0, stream>>>(ML);
  // f*mask logits
  gemm256<0, true><<<dim3(N / 256, N / 256), 512, 0, stream>>>(
      th16, ph16, nullptr, ML, fm, N, N, IC);
  softmax_f_k<<<N, 256, 0, stream>>>(fm, f_out);
  // y = P @ g_x (NT via gT16), XCD-grouped on A rows
  gemm_nt<0, false, false, true, 0><<<dim3(IC / 128, N / 128), 256, 0, stream>>>(
      fm, gT16, nullptr, nullptr, nullptr, nullptr, y16, N, IC, N);
  // z = y @ W_w^T + W_b + x
  gemm_nt<1, false, true, false, 0><<<dim3(C / 128, N / 128), 256, 0, stream>>>(
      y16, Wwb, W_b, nullptr, x, z_out, nullptr, N, C, IC);
}

// Round 10
// 1142.525 us; speedup vs baseline: 4.2551x; 4.2551x over previous
//
#include <hip/hip_runtime.h>
#include <hip/hip_bf16.h>

typedef __bf16 bf16_t;
typedef __bf16 bf16x8 __attribute__((ext_vector_type(8)));
typedef float f32x4 __attribute__((ext_vector_type(4)));

#define GLOAD16(gp, lp) __builtin_amdgcn_global_load_lds(                      \
    (const __attribute__((address_space(1))) void*)(gp),                       \
    (__attribute__((address_space(3))) void*)(lp), 16, 0, 0)
#define BARRIER() asm volatile("s_barrier" ::: "memory")
#define VMC(n) asm volatile("s_waitcnt vmcnt(" #n ")" ::: "memory")
#define LGK0()                                                                 \
  do {                                                                         \
    asm volatile("s_waitcnt lgkmcnt(0)" ::: "memory");                         \
    __builtin_amdgcn_sched_barrier(0);                                         \
  } while (0)

// ---------------- cast fp32 -> bf16 (vectorized x8) ----------------
__global__ __launch_bounds__(256) void cast_f32_bf16_k(
    const float* __restrict__ in, bf16_t* __restrict__ out, long n8) {
  long i = (long)blockIdx.x * blockDim.x + threadIdx.x;
  long stride = (long)gridDim.x * blockDim.x;
  for (; i < n8; i += stride) {
    long e = i * 8;
    float4 a = *(const float4*)(in + e);
    float4 b = *(const float4*)(in + e + 4);
    bf16x8 o;
    o[0] = (__bf16)a.x; o[1] = (__bf16)a.y; o[2] = (__bf16)a.z; o[3] = (__bf16)a.w;
    o[4] = (__bf16)b.x; o[5] = (__bf16)b.y; o[6] = (__bf16)b.z; o[7] = (__bf16)b.w;
    *(bf16x8*)(out + e) = o;
  }
}

// ============ 128x256-tile 4-wave GEMM, BK=32, 2x24KB LDS double-buffer ====
// 48KB LDS + <=256 VGPR (launch_bounds(256,2)) -> 2 blocks/CU: two drifting
// barrier domains; one block's DS bursts overlap the other's MFMA (m114).
// Per K-step: VMC(0)+barrier, stage 6 gloads, 2 phases {ds_read, lgkm(0),
// 16 MFMA}. LDS rows 64B; 16B slot ^= (row>>1)&3; staging inverse-swizzles
// the global source (linear LDS dest). EMASK epilogue folds the mask softmax:
// v *= exp(ml - mrow)*invrow.
template <int BIAS, bool EMASK>
__global__ __launch_bounds__(256, 2) void gemm128(
    const bf16_t* __restrict__ A, const bf16_t* __restrict__ B,
    const float* __restrict__ bias, const bf16_t* __restrict__ ml,
    const float* __restrict__ mrow, const float* __restrict__ invrow,
    bf16_t* __restrict__ out, int M, int N, int K) {
  __shared__ __align__(1024) char lds[49152];
  const int tid = threadIdx.x;
  const int gx = N >> 8;
  int bid = blockIdx.y * gx + blockIdx.x;
  const int nwg = gridDim.x * gridDim.y;  // multiple of 8 for our shapes
  const int cpx = nwg >> 3;
  bid = (bid & 7) * cpx + (bid >> 3);     // XCD-aware bijective swizzle
  const long row0 = (long)(bid / gx) * 128;
  const long col0 = (long)(bid % gx) * 256;

  const int w = tid >> 6, lane = tid & 63;  // w = column-wave 0..3
  const int fr = lane & 15, fq = lane >> 4;
  const int sx = (fr >> 1) & 3;             // read-side swizzle (lane-const)

  // fragment byte offsets within one 24KB buffer (A at 0, B at 8192)
  int aoff[8], boff[4];
#pragma unroll
  for (int i = 0; i < 8; ++i)
    aoff[i] = (i * 16 + fr) * 64 + ((fq ^ sx) << 4);
#pragma unroll
  for (int j = 0; j < 4; ++j)
    boff[j] = 8192 + (w * 64 + j * 16 + fr) * 64 + ((fq ^ sx) << 4);

  // staging: all chunks share row rr = tid>>2 (+64k offsets keep (row>>1)&3)
  const int rr = tid >> 2;
  const int ss = (tid & 3) ^ ((rr >> 1) & 3);
  const bf16_t* Asrc = A + (row0 + rr) * (long)K + ss * 8;
  const bf16_t* Bsrc = B + (col0 + rr) * (long)K + ss * 8;
  const long K64 = 64L * K, K128 = 128L * K, K192 = 192L * K;
  const int db = w * 1024;  // wave-uniform dest base (+ lane*16 in HW)

#define STAGE(T)                                                               \
  {                                                                            \
    char* nb_ = lds + (((T)&1) ? 24576 : 0);                                   \
    const long ko_ = (long)(T)*32;                                             \
    GLOAD16(Asrc + ko_, nb_ + db);                                             \
    GLOAD16(Asrc + K64 + ko_, nb_ + 4096 + db);                                \
    GLOAD16(Bsrc + ko_, nb_ + 8192 + db);                                      \
    GLOAD16(Bsrc + K64 + ko_, nb_ + 12288 + db);                               \
    GLOAD16(Bsrc + K128 + ko_, nb_ + 16384 + db);                              \
    GLOAD16(Bsrc + K192 + ko_, nb_ + 20480 + db);                              \
  }

  f32x4 acc[8][4] = {};
  bf16x8 a0[4], a1[4], bv[4];
  const int NT = K >> 5;  // >= 2

  STAGE(0);

  for (int T = 0; T < NT; ++T) {
    char* buf = lds + ((T & 1) ? 24576 : 0);
    VMC(0);
    BARRIER();
    if (T < NT - 1) STAGE(T + 1);
    // phase 1: A rows 0..3 + B
#pragma unroll
    for (int i = 0; i < 4; ++i) a0[i] = *(const bf16x8*)(buf + aoff[i]);
#pragma unroll
    for (int j = 0; j < 4; ++j) bv[j] = *(const bf16x8*)(buf + boff[j]);
    LGK0();
    __builtin_amdgcn_s_setprio(1);
#pragma unroll
    for (int i = 0; i < 4; ++i)
#pragma unroll
      for (int j = 0; j < 4; ++j)
        acc[i][j] = __builtin_amdgcn_mfma_f32_16x16x32_bf16(a0[i], bv[j],
                                                            acc[i][j], 0, 0, 0);
    __builtin_amdgcn_s_setprio(0);
    // phase 2: A rows 4..7
#pragma unroll
    for (int i = 0; i < 4; ++i) a1[i] = *(const bf16x8*)(buf + aoff[4 + i]);
    LGK0();
    __builtin_amdgcn_s_setprio(1);
#pragma unroll
    for (int i = 0; i < 4; ++i)
#pragma unroll
      for (int j = 0; j < 4; ++j)
        acc[4 + i][j] = __builtin_amdgcn_mfma_f32_16x16x32_bf16(
            a1[i], bv[j], acc[4 + i][j], 0, 0, 0);
    __builtin_amdgcn_s_setprio(0);
  }
#undef STAGE

  // epilogue: C/D layout col=lane&15, row=(lane>>4)*4+r
#pragma unroll
  for (int i = 0; i < 8; ++i)
#pragma unroll
    for (int j = 0; j < 4; ++j)
#pragma unroll
      for (int r = 0; r < 4; ++r) {
        long gi = row0 + i * 16 + fq * 4 + r;
        long gj = col0 + w * 64 + j * 16 + fr;
        float v = acc[i][j][r];
        if (BIAS == 1) v += bias[gj];
        long idx = gi * (long)N + gj;
        if (EMASK)
          v *= __expf((float)ml[idx] - mrow[gi]) * invrow[gi];
        out[idx] = (bf16_t)v;
      }
}

// ---------------- NT GEMM (m97 128x128), slot-swizzled, XCD-grouped --------
// GROUP 0: blocks sharing an A row-tile grouped on one XCD (requires gy%8==0)
// GROUP 1: blocks sharing a B col-tile grouped on one XCD (requires gx%8==0)
template <int BIAS, bool MUL, bool RES, bool OUTBF16, int GROUP>
__global__ __launch_bounds__(256) void gemm_nt(
    const bf16_t* __restrict__ A, const bf16_t* __restrict__ B,
    const float* __restrict__ bias, const bf16_t* __restrict__ mulm,
    const float* __restrict__ res, float* __restrict__ outf,
    bf16_t* __restrict__ outb, int M, int N, int K) {
  __shared__ bf16_t As[128 * 32];
  __shared__ bf16_t Bs[128 * 32];
  const int tid = threadIdx.x;
  const int gx = gridDim.x, gy = gridDim.y;
  const int n = blockIdx.y * gx + blockIdx.x;
  const int xcd = n & 7, q = n >> 3;
  int br, bc;
  if (GROUP == 0) { br = xcd + 8 * (q / gx); bc = q % gx; }
  else            { bc = xcd + 8 * (q / gy); br = q % gy; }
  const long row0 = (long)br * 128;
  const long col0 = (long)bc * 128;
  const int wid = tid >> 6, lane = tid & 63;
  const int wr = (wid >> 1) * 64;
  const int wc = (wid & 1) * 64;
  const int fr = lane & 15, fq = lane >> 4;
  const int sx = (fr >> 1) & 3;
  const int srow = tid >> 2;
  const int scol = ((tid & 3) ^ ((srow >> 1) & 3)) * 8;  // inverse-swz source

  f32x4 acc[4][4] = {};

  const bf16_t* Ag = A + (row0 + srow) * (long)K + scol;
  const bf16_t* Bg = B + (col0 + srow) * (long)K + scol;
  const long k64 = 64L * K;
  bf16_t* ldsA = As + wid * 512;
  bf16_t* ldsB = Bs + wid * 512;

  for (int k0 = 0; k0 < K; k0 += 32) {
    GLOAD16(Ag + k0, ldsA);
    GLOAD16(Ag + k0 + k64, ldsA + 2048);
    GLOAD16(Bg + k0, ldsB);
    GLOAD16(Bg + k0 + k64, ldsB + 2048);
    __syncthreads();
    bf16x8 av[4], bv[4];
#pragma unroll
    for (int i = 0; i < 4; i++)
      av[i] = *(const bf16x8*)(As + (wr + i * 16 + fr) * 32 + ((fq ^ sx) << 3));
#pragma unroll
    for (int j = 0; j < 4; j++)
      bv[j] = *(const bf16x8*)(Bs + (wc + j * 16 + fr) * 32 + ((fq ^ sx) << 3));
#pragma unroll
    for (int i = 0; i < 4; i++)
#pragma unroll
      for (int j = 0; j < 4; j++)
        acc[i][j] = __builtin_amdgcn_mfma_f32_16x16x32_bf16(av[i], bv[j],
                                                            acc[i][j], 0, 0, 0);
    __syncthreads();
  }

#pragma unroll
  for (int i = 0; i < 4; i++) {
#pragma unroll
    for (int j = 0; j < 4; j++) {
#pragma unroll
      for (int r = 0; r < 4; r++) {
        long gi = row0 + wr + i * 16 + fq * 4 + r;
        long gj = col0 + wc + j * 16 + fr;
        float v = acc[i][j][r];
        if (BIAS == 1) v += bias[gj];
        if (BIAS == 2) v += bias[gi];
        long idx = gi * (long)N + gj;
        if (MUL) v *= (float)mulm[idx];
        if (RES) v += res[idx];
        if (OUTBF16) outb[idx] = (bf16_t)v;
        else outf[idx] = v;
      }
    }
  }
}

// ------- row softmax stats over 8192 cols: write per-row max and 1/sum ----
__global__ __launch_bounds__(256) void softmax_stats(
    const bf16_t* __restrict__ buf, float* __restrict__ mrow,
    float* __restrict__ invrow) {
  const long row = blockIdx.x;
  const bf16_t* p = buf + row * 8192;
  const int t = threadIdx.x;
  float v[32];
#pragma unroll
  for (int i = 0; i < 4; i++) {
    bf16x8 raw = *(const bf16x8*)(p + t * 32 + i * 8);
#pragma unroll
    for (int j = 0; j < 8; j++) v[i * 8 + j] = (float)raw[j];
  }
  float m = -1e30f;
#pragma unroll
  for (int i = 0; i < 32; i++) m = fmaxf(m, v[i]);
  for (int off = 32; off; off >>= 1) m = fmaxf(m, __shfl_xor(m, off, 64));
  __shared__ float redm[4], reds[4];
  if ((t & 63) == 0) redm[t >> 6] = m;
  __syncthreads();
  m = fmaxf(fmaxf(redm[0], redm[1]), fmaxf(redm[2], redm[3]));
  float s = 0.f;
#pragma unroll
  for (int i = 0; i < 32; i++) s += __expf(v[i] - m);
  for (int off = 32; off; off >>= 1) s += __shfl_xor(s, off, 64);
  if ((t & 63) == 0) reds[t >> 6] = s;
  __syncthreads();
  if (t == 0) {
    s = reds[0] + reds[1] + reds[2] + reds[3];
    mrow[row] = m;
    invrow[row] = 1.0f / s;
  }
}

// --------- row softmax: bf16 logits in, fp32 out + bf16 in-place ----------
__global__ __launch_bounds__(256) void softmax_f_k(bf16_t* __restrict__ fm,
                                                   float* __restrict__ outf) {
  const long row = blockIdx.x;
  bf16_t* p = fm + row * 8192;
  float* q = outf + row * 8192;
  const int t = threadIdx.x;
  float v[32];
#pragma unroll
  for (int i = 0; i < 4; i++) {
    bf16x8 raw = *(const bf16x8*)(p + t * 32 + i * 8);
#pragma unroll
    for (int j = 0; j < 8; j++) v[i * 8 + j] = (float)raw[j];
  }
  float m = -1e30f;
#pragma unroll
  for (int i = 0; i < 32; i++) m = fmaxf(m, v[i]);
  for (int off = 32; off; off >>= 1) m = fmaxf(m, __shfl_xor(m, off, 64));
  __shared__ float redm[4], reds[4];
  if ((t & 63) == 0) redm[t >> 6] = m;
  __syncthreads();
  m = fmaxf(fmaxf(redm[0], redm[1]), fmaxf(redm[2], redm[3]));
  float s = 0.f;
#pragma unroll
  for (int i = 0; i < 32; i++) {
    v[i] = __expf(v[i] - m);
    s += v[i];
  }
  for (int off = 32; off; off >>= 1) s += __shfl_xor(s, off, 64);
  if ((t & 63) == 0) reds[t >> 6] = s;
  __syncthreads();
  s = reds[0] + reds[1] + reds[2] + reds[3];
  float inv = 1.0f / s;
#pragma unroll
  for (int i = 0; i < 8; i++) {
    float4 o;
    o.x = v[i * 4 + 0] * inv;
    o.y = v[i * 4 + 1] * inv;
    o.z = v[i * 4 + 2] * inv;
    o.w = v[i * 4 + 3] * inv;
    *(float4*)(q + t * 32 + i * 4) = o;
  }
#pragma unroll
  for (int i = 0; i < 4; i++) {
    bf16x8 o;
#pragma unroll
    for (int j = 0; j < 8; j++) o[j] = (bf16_t)(v[i * 8 + j] * inv);
    *(bf16x8*)(p + t * 32 + i * 8) = o;
  }
}

// ---------------------------------------------------------------------------
extern "C" void kernel_launch(void* const* d_in, const int* in_sizes, int n_in,
                              void* d_out, int out_size, void* d_ws,
                              size_t ws_size, hipStream_t stream) {
  const int N = 8192, C = 2048, IC = 1024;
  const float* x = (const float*)d_in[0];
  const float* theta_w = (const float*)d_in[1];
  const float* theta_b = (const float*)d_in[2];
  const float* phi_w = (const float*)d_in[3];
  const float* phi_b = (const float*)d_in[4];
  const float* g_w = (const float*)d_in[5];
  const float* g_b = (const float*)d_in[6];
  const float* W_w = (const float*)d_in[7];
  const float* W_b = (const float*)d_in[8];
  const float* mask_w = (const float*)d_in[9];
  const float* mask_b = (const float*)d_in[10];

  float* z_out = (float*)d_out;            // [N,C] fp32
  float* f_out = z_out + (long)N * C;      // [N,N] fp32

  // d_out-hosted scratch (dead before those regions' final writes):
  bf16_t* ML = (bf16_t*)f_out;             // [N,N] bf16 raw mask logits
  bf16_t* th16 = (bf16_t*)z_out;           // [N,IC]
  bf16_t* ph16 = th16 + (long)N * IC;      // [N,IC]
  bf16_t* gT16 = ph16 + (long)N * IC;      // [IC,N]

  char* w = (char*)d_ws;
  bf16_t* xb = (bf16_t*)w;      w += (long)N * C * 2;
  bf16_t* mwb = (bf16_t*)w;     w += (long)N * C * 2;
  bf16_t* thwb = (bf16_t*)w;    w += (long)IC * C * 2;
  bf16_t* phwb = (bf16_t*)w;    w += (long)IC * C * 2;
  bf16_t* gwb = (bf16_t*)w;     w += (long)IC * C * 2;
  bf16_t* Wwb = (bf16_t*)w;     w += (long)C * IC * 2;
  bf16_t* fm = (bf16_t*)w;      w += (long)N * N * 2;   // f*mask logits -> P
  bf16_t* y16 = (bf16_t*)w;     w += (long)N * IC * 2;
  float* mrowb = (float*)w;     w += (long)N * 4;       // mask-softmax max
  float* invrowb = (float*)w;   w += (long)N * 4;       // mask-softmax 1/sum

  cast_f32_bf16_k<<<8192, 256, 0, stream>>>(x, xb, (long)N * C / 8);
  cast_f32_bf16_k<<<8192, 256, 0, stream>>>(mask_w, mwb, (long)N * C / 8);
  cast_f32_bf16_k<<<1024, 256, 0, stream>>>(theta_w, thwb, (long)IC * C / 8);
  cast_f32_bf16_k<<<1024, 256, 0, stream>>>(phi_w, phwb, (long)IC * C / 8);
  cast_f32_bf16_k<<<1024, 256, 0, stream>>>(g_w, gwb, (long)IC * C / 8);
  cast_f32_bf16_k<<<1024, 256, 0, stream>>>(W_w, Wwb, (long)C * IC / 8);

  // projections (128^2 kernel, XCD-grouped)
  gemm_nt<1, false, false, true, 0><<<dim3(IC / 128, N / 128), 256, 0, stream>>>(
      xb, thwb, theta_b, nullptr, nullptr, nullptr, th16, N, IC, C);
  gemm_nt<1, false, false, true, 0><<<dim3(IC / 128, N / 128), 256, 0, stream>>>(
      xb, phwb, phi_b, nullptr, nullptr, nullptr, ph16, N, IC, C);
  gemm_nt<2, false, false, true, 1><<<dim3(N / 128, IC / 128), 256, 0, stream>>>(
      gwb, xb, g_b, nullptr, nullptr, nullptr, gT16, IC, N, C);
  // mask logits (128x256 2-blocks/CU kernel), bias per col -> raw ML
  gemm128<1, false><<<dim3(N / 256, N / 128), 256, 0, stream>>>(
      xb, mwb, mask_b, nullptr, nullptr, nullptr, ML, N, N, C);
  // mask softmax stats only (read-only pass)
  softmax_stats<<<N, 256, 0, stream>>>(ML, mrowb, invrowb);
  // f*mask logits with folded exp-mask epilogue
  gemm128<0, true><<<dim3(N / 256, N / 128), 256, 0, stream>>>(
      th16, ph16, nullptr, ML, mrowb, invrowb, fm, N, N, IC);
  softmax_f_k<<<N, 256, 0, stream>>>(fm, f_out);
  // y = P @ g_x (NT via gT16), XCD-grouped on A rows
  gemm_nt<0, false, false, true, 0><<<dim3(IC / 128, N / 128), 256, 0, stream>>>(
      fm, gT16, nullptr, nullptr, nullptr, nullptr, y16, N, IC, N);
  // z = y @ W_w^T + W_b + x
  gemm_nt<1, false, true, false, 0><<<dim3(C / 128, N / 128), 256, 0, stream>>>(
      y16, Wwb, W_b, nullptr, x, z_out, nullptr, N, C, IC);
}

// Round 11
// 1078.604 us; speedup vs baseline: 4.5072x; 1.0593x over previous
//
#include <hip/hip_runtime.h>
#include <hip/hip_bf16.h>

typedef __bf16 bf16_t;
typedef __bf16 bf16x8 __attribute__((ext_vector_type(8)));
typedef float f32x4 __attribute__((ext_vector_type(4)));

#define GLOAD16(gp, lp) __builtin_amdgcn_global_load_lds(                      \
    (const __attribute__((address_space(1))) void*)(gp),                       \
    (__attribute__((address_space(3))) void*)(lp), 16, 0, 0)
#define BARRIER() asm volatile("s_barrier" ::: "memory")
#define VMC(n) asm volatile("s_waitcnt vmcnt(" #n ")" ::: "memory")
#define LGK0()                                                                 \
  do {                                                                         \
    asm volatile("s_waitcnt lgkmcnt(0)" ::: "memory");                         \
    __builtin_amdgcn_sched_barrier(0);                                         \
  } while (0)

// ---------------- cast fp32 -> bf16 (vectorized x8) ----------------
__global__ __launch_bounds__(256) void cast_f32_bf16_k(
    const float* __restrict__ in, bf16_t* __restrict__ out, long n8) {
  long i = (long)blockIdx.x * blockDim.x + threadIdx.x;
  long stride = (long)gridDim.x * blockDim.x;
  for (; i < n8; i += stride) {
    long e = i * 8;
    float4 a = *(const float4*)(in + e);
    float4 b = *(const float4*)(in + e + 4);
    bf16x8 o;
    o[0] = (__bf16)a.x; o[1] = (__bf16)a.y; o[2] = (__bf16)a.z; o[3] = (__bf16)a.w;
    o[4] = (__bf16)b.x; o[5] = (__bf16)b.y; o[6] = (__bf16)b.z; o[7] = (__bf16)b.w;
    *(bf16x8*)(out + e) = o;
  }
}

// ============ 256x256-tile 8-wave GEMM, BK=64, m201-style 4-phase/K-tile ===
// LDS 128KB: 2 buf x {A 256x128B, B 256x128B}. Per phase: small ds_read burst
// + 1 half-tile stage + 2 barriers + 16 MFMA; counted vmcnt(2) once per tile
// at ph3 (never drained in steady state). Live frags: 1 A set + 2 B sets =
// 64 VGPR; acc 128. Swizzle: slot ^= fr&7 on 128B rows (2-way free); staging
// inverse-swizzles the per-lane global source, linear LDS dest.
template <int BIAS, bool EMASK>
__global__ __launch_bounds__(512, 2) void gemm256p(
    const bf16_t* __restrict__ A, const bf16_t* __restrict__ B,
    const float* __restrict__ bias, const bf16_t* __restrict__ ml,
    const float* __restrict__ mrow, const float* __restrict__ invrow,
    bf16_t* __restrict__ out, int M, int N, int K) {
  __shared__ __align__(1024) char lds[131072];
  const int tid = threadIdx.x;
  const int gx = N >> 8;
  int bid = blockIdx.y * gx + blockIdx.x;
  const int nwg = gridDim.x * gridDim.y;  // multiple of 8 for our shapes
  const int cpx = nwg >> 3;
  bid = (bid & 7) * cpx + (bid >> 3);     // XCD-aware bijective swizzle
  const long row0 = (long)(bid / gx) * 256;
  const long col0 = (long)(bid % gx) * 256;
  const long Kl = K;

  const int w = tid >> 6, lane = tid & 63;
  const int wm = w >> 2, wn = w & 3;      // 2M x 4N waves, per-wave out 128x64
  const int fr = lane & 15, fq = lane >> 4;

  // read-side: row stride 128B; 16B slot (kk*4+fq) ^ (fr&7)
  const int rowA0 = (wm * 128 + fr) * 128;
  const int rowB0 = 32768 + (wn * 64 + fr) * 128;
  const int sl0 = ((fq ^ (fr & 7)) << 4);           // kk=0
  const int sl1 = (((4 | fq) ^ (fr & 7)) << 4);     // kk=1

  // staging: thread's phys bytes p=tid*16 (+8192) of each 16KB half;
  // row_local = p>>7, slot=(p>>4)&7, src chunk = slot ^ (row_local&7)
  const int srow = 8 * w + (lane >> 3);             // 0..63 (load1: +64)
  const int schk = (lane & 7) ^ (lane >> 3);
  const bf16_t* Asrc = A + (row0 + srow) * Kl + schk * 8;
  const bf16_t* Bsrc = B + (col0 + srow) * Kl + schk * 8;
  const int dstb = w * 1024;                        // + lane*16 in HW

#define STG_A(h, U)                                                            \
  {                                                                            \
    const bf16_t* s_ = Asrc + (long)(h)*128 * Kl + (long)(U)*64;               \
    char* d_ = lds + (((U)&1) * 65536) + (h)*16384 + dstb;                     \
    GLOAD16(s_, d_);                                                           \
    GLOAD16(s_ + 64 * Kl, d_ + 8192);                                          \
  }
#define STG_B(h, U)                                                            \
  {                                                                            \
    const bf16_t* s_ = Bsrc + (long)(h)*128 * Kl + (long)(U)*64;               \
    char* d_ = lds + (((U)&1) * 65536) + 32768 + (h)*16384 + dstb;             \
    GLOAD16(s_, d_);                                                           \
    GLOAD16(s_ + 64 * Kl, d_ + 8192);                                          \
  }
#define RDA(lo)                                                                \
  {                                                                            \
    _Pragma("unroll") for (int i = 0; i < 4; ++i) {                            \
      const char* rb = buf + rowA0 + ((lo) ? 0 : 8192) + i * 2048;             \
      aS[i * 2] = *(const bf16x8*)(rb + sl0);                                  \
      aS[i * 2 + 1] = *(const bf16x8*)(rb + sl1);                              \
    }                                                                          \
  }
#define RDB(dst, hi)                                                           \
  {                                                                            \
    _Pragma("unroll") for (int j = 0; j < 2; ++j) {                            \
      const char* rb = buf + rowB0 + ((hi) ? 4096 : 0) + j * 2048;             \
      dst[j * 2] = *(const bf16x8*)(rb + sl0);                                 \
      dst[j * 2 + 1] = *(const bf16x8*)(rb + sl1);                             \
    }                                                                          \
  }
#define QUAD(BV, I0, J0)                                                       \
  {                                                                            \
    __builtin_amdgcn_s_setprio(1);                                             \
    _Pragma("unroll") for (int i = 0; i < 4; ++i)                              \
        _Pragma("unroll") for (int j = 0; j < 2; ++j)                          \
            _Pragma("unroll") for (int kk = 0; kk < 2; ++kk)                   \
                acc[I0 + i][J0 + j] = __builtin_amdgcn_mfma_f32_16x16x32_bf16( \
                    aS[i * 2 + kk], BV[j * 2 + kk], acc[I0 + i][J0 + j], 0, 0, \
                    0);                                                        \
    __builtin_amdgcn_s_setprio(0);                                             \
  }

  f32x4 acc[8][4] = {};
  bf16x8 aS[8], bLo[4], bHi[4];
  const int NT = K >> 6;  // >= 3

  // prologue: tile 0 (4 halves) + A0(1); publish tile 0 with A0(1) in flight
  STG_A(0, 0); STG_A(1, 0); STG_B(0, 0); STG_B(1, 0); STG_A(0, 1);
  VMC(2);
  BARRIER();

  for (int T = 0; T < NT; ++T) {
    char* buf = lds + (T & 1) * 65536;
    // ph0: A-lo + B-lo (12 reads); stage A1(T+1)
    RDA(true);
    RDB(bLo, false);
    if (T < NT - 1) STG_A(1, T + 1);
    BARRIER();
    LGK0();
    QUAD(bLo, 0, 0);
    BARRIER();
    // ph1: B-hi (4 reads); stage B0(T+1)
    RDB(bHi, true);
    if (T < NT - 1) STG_B(0, T + 1);
    BARRIER();
    LGK0();
    QUAD(bHi, 0, 2);
    BARRIER();
    // ph2: A-hi (8 reads); stage B1(T+1)
    RDA(false);
    if (T < NT - 1) STG_B(1, T + 1);
    BARRIER();
    LGK0();
    QUAD(bHi, 4, 2);
    BARRIER();
    // ph3: stage A0(T+2); counted vmcnt publishes tile T+1; 16 MFMA
    if (T < NT - 2) {
      STG_A(0, T + 2);
      VMC(2);
    } else if (T == NT - 2) {
      VMC(0);
    }
    QUAD(bLo, 4, 0);
    BARRIER();
  }
#undef STG_A
#undef STG_B
#undef RDA
#undef RDB
#undef QUAD

  // epilogue: C/D layout col=lane&15, row=(lane>>4)*4+r
#pragma unroll
  for (int i = 0; i < 8; ++i)
#pragma unroll
    for (int j = 0; j < 4; ++j)
#pragma unroll
      for (int r = 0; r < 4; ++r) {
        long gi = row0 + wm * 128 + i * 16 + fq * 4 + r;
        long gj = col0 + wn * 64 + j * 16 + fr;
        float v = acc[i][j][r];
        if (BIAS == 1) v += bias[gj];
        long idx = gi * (long)N + gj;
        if (EMASK) v *= __expf((float)ml[idx] - mrow[gi]) * invrow[gi];
        out[idx] = (bf16_t)v;
      }
}

// ---------------- NT GEMM (m97 128x128), slot-swizzled, XCD-grouped --------
// GROUP 0: blocks sharing an A row-tile grouped on one XCD (requires gy%8==0)
// GROUP 1: blocks sharing a B col-tile grouped on one XCD (requires gx%8==0)
template <int BIAS, bool MUL, bool RES, bool OUTBF16, int GROUP>
__global__ __launch_bounds__(256) void gemm_nt(
    const bf16_t* __restrict__ A, const bf16_t* __restrict__ B,
    const float* __restrict__ bias, const bf16_t* __restrict__ mulm,
    const float* __restrict__ res, float* __restrict__ outf,
    bf16_t* __restrict__ outb, int M, int N, int K) {
  __shared__ bf16_t As[128 * 32];
  __shared__ bf16_t Bs[128 * 32];
  const int tid = threadIdx.x;
  const int gx = gridDim.x, gy = gridDim.y;
  const int n = blockIdx.y * gx + blockIdx.x;
  const int xcd = n & 7, q = n >> 3;
  int br, bc;
  if (GROUP == 0) { br = xcd + 8 * (q / gx); bc = q % gx; }
  else            { bc = xcd + 8 * (q / gy); br = q % gy; }
  const long row0 = (long)br * 128;
  const long col0 = (long)bc * 128;
  const int wid = tid >> 6, lane = tid & 63;
  const int wr = (wid >> 1) * 64;
  const int wc = (wid & 1) * 64;
  const int fr = lane & 15, fq = lane >> 4;
  const int sx = (fr >> 1) & 3;
  const int srow = tid >> 2;
  const int scol = ((tid & 3) ^ ((srow >> 1) & 3)) * 8;  // inverse-swz source

  f32x4 acc[4][4] = {};

  const bf16_t* Ag = A + (row0 + srow) * (long)K + scol;
  const bf16_t* Bg = B + (col0 + srow) * (long)K + scol;
  const long k64 = 64L * K;
  bf16_t* ldsA = As + wid * 512;
  bf16_t* ldsB = Bs + wid * 512;

  for (int k0 = 0; k0 < K; k0 += 32) {
    GLOAD16(Ag + k0, ldsA);
    GLOAD16(Ag + k0 + k64, ldsA + 2048);
    GLOAD16(Bg + k0, ldsB);
    GLOAD16(Bg + k0 + k64, ldsB + 2048);
    __syncthreads();
    bf16x8 av[4], bv[4];
#pragma unroll
    for (int i = 0; i < 4; i++)
      av[i] = *(const bf16x8*)(As + (wr + i * 16 + fr) * 32 + ((fq ^ sx) << 3));
#pragma unroll
    for (int j = 0; j < 4; j++)
      bv[j] = *(const bf16x8*)(Bs + (wc + j * 16 + fr) * 32 + ((fq ^ sx) << 3));
#pragma unroll
    for (int i = 0; i < 4; i++)
#pragma unroll
      for (int j = 0; j < 4; j++)
        acc[i][j] = __builtin_amdgcn_mfma_f32_16x16x32_bf16(av[i], bv[j],
                                                            acc[i][j], 0, 0, 0);
    __syncthreads();
  }

#pragma unroll
  for (int i = 0; i < 4; i++) {
#pragma unroll
    for (int j = 0; j < 4; j++) {
#pragma unroll
      for (int r = 0; r < 4; r++) {
        long gi = row0 + wr + i * 16 + fq * 4 + r;
        long gj = col0 + wc + j * 16 + fr;
        float v = acc[i][j][r];
        if (BIAS == 1) v += bias[gj];
        if (BIAS == 2) v += bias[gi];
        long idx = gi * (long)N + gj;
        if (MUL) v *= (float)mulm[idx];
        if (RES) v += res[idx];
        if (OUTBF16) outb[idx] = (bf16_t)v;
        else outf[idx] = v;
      }
    }
  }
}

// ------- row softmax stats over 8192 cols: write per-row max and 1/sum ----
__global__ __launch_bounds__(256) void softmax_stats(
    const bf16_t* __restrict__ buf, float* __restrict__ mrow,
    float* __restrict__ invrow) {
  const long row = blockIdx.x;
  const bf16_t* p = buf + row * 8192;
  const int t = threadIdx.x;
  float v[32];
#pragma unroll
  for (int i = 0; i < 4; i++) {
    bf16x8 raw = *(const bf16x8*)(p + t * 32 + i * 8);
#pragma unroll
    for (int j = 0; j < 8; j++) v[i * 8 + j] = (float)raw[j];
  }
  float m = -1e30f;
#pragma unroll
  for (int i = 0; i < 32; i++) m = fmaxf(m, v[i]);
  for (int off = 32; off; off >>= 1) m = fmaxf(m, __shfl_xor(m, off, 64));
  __shared__ float redm[4], reds[4];
  if ((t & 63) == 0) redm[t >> 6] = m;
  __syncthreads();
  m = fmaxf(fmaxf(redm[0], redm[1]), fmaxf(redm[2], redm[3]));
  float s = 0.f;
#pragma unroll
  for (int i = 0; i < 32; i++) s += __expf(v[i] - m);
  for (int off = 32; off; off >>= 1) s += __shfl_xor(s, off, 64);
  if ((t & 63) == 0) reds[t >> 6] = s;
  __syncthreads();
  if (t == 0) {
    s = reds[0] + reds[1] + reds[2] + reds[3];
    mrow[row] = m;
    invrow[row] = 1.0f / s;
  }
}

// --------- row softmax: bf16 logits in, fp32 out + bf16 in-place ----------
__global__ __launch_bounds__(256) void softmax_f_k(bf16_t* __restrict__ fm,
                                                   float* __restrict__ outf) {
  const long row = blockIdx.x;
  bf16_t* p = fm + row * 8192;
  float* q = outf + row * 8192;
  const int t = threadIdx.x;
  float v[32];
#pragma unroll
  for (int i = 0; i < 4; i++) {
    bf16x8 raw = *(const bf16x8*)(p + t * 32 + i * 8);
#pragma unroll
    for (int j = 0; j < 8; j++) v[i * 8 + j] = (float)raw[j];
  }
  float m = -1e30f;
#pragma unroll
  for (int i = 0; i < 32; i++) m = fmaxf(m, v[i]);
  for (int off = 32; off; off >>= 1) m = fmaxf(m, __shfl_xor(m, off, 64));
  __shared__ float redm[4], reds[4];
  if ((t & 63) == 0) redm[t >> 6] = m;
  __syncthreads();
  m = fmaxf(fmaxf(redm[0], redm[1]), fmaxf(redm[2], redm[3]));
  float s = 0.f;
#pragma unroll
  for (int i = 0; i < 32; i++) {
    v[i] = __expf(v[i] - m);
    s += v[i];
  }
  for (int off = 32; off; off >>= 1) s += __shfl_xor(s, off, 64);
  if ((t & 63) == 0) reds[t >> 6] = s;
  __syncthreads();
  s = reds[0] + reds[1] + reds[2] + reds[3];
  float inv = 1.0f / s;
#pragma unroll
  for (int i = 0; i < 8; i++) {
    float4 o;
    o.x = v[i * 4 + 0] * inv;
    o.y = v[i * 4 + 1] * inv;
    o.z = v[i * 4 + 2] * inv;
    o.w = v[i * 4 + 3] * inv;
    *(float4*)(q + t * 32 + i * 4) = o;
  }
#pragma unroll
  for (int i = 0; i < 4; i++) {
    bf16x8 o;
#pragma unroll
    for (int j = 0; j < 8; j++) o[j] = (bf16_t)(v[i * 8 + j] * inv);
    *(bf16x8*)(p + t * 32 + i * 8) = o;
  }
}

// ---------------------------------------------------------------------------
extern "C" void kernel_launch(void* const* d_in, const int* in_sizes, int n_in,
                              void* d_out, int out_size, void* d_ws,
                              size_t ws_size, hipStream_t stream) {
  const int N = 8192, C = 2048, IC = 1024;
  const float* x = (const float*)d_in[0];
  const float* theta_w = (const float*)d_in[1];
  const float* theta_b = (const float*)d_in[2];
  const float* phi_w = (const float*)d_in[3];
  const float* phi_b = (const float*)d_in[4];
  const float* g_w = (const float*)d_in[5];
  const float* g_b = (const float*)d_in[6];
  const float* W_w = (const float*)d_in[7];
  const float* W_b = (const float*)d_in[8];
  const float* mask_w = (const float*)d_in[9];
  const float* mask_b = (const float*)d_in[10];

  float* z_out = (float*)d_out;            // [N,C] fp32
  float* f_out = z_out + (long)N * C;      // [N,N] fp32

  // d_out-hosted scratch (dead before those regions' final writes):
  bf16_t* ML = (bf16_t*)f_out;             // [N,N] bf16 raw mask logits
  bf16_t* th16 = (bf16_t*)z_out;           // [N,IC]
  bf16_t* ph16 = th16 + (long)N * IC;      // [N,IC]
  bf16_t* gT16 = ph16 + (long)N * IC;      // [IC,N]

  char* w = (char*)d_ws;
  bf16_t* xb = (bf16_t*)w;      w += (long)N * C * 2;
  bf16_t* mwb = (bf16_t*)w;     w += (long)N * C * 2;
  bf16_t* thwb = (bf16_t*)w;    w += (long)IC * C * 2;
  bf16_t* phwb = (bf16_t*)w;    w += (long)IC * C * 2;
  bf16_t* gwb = (bf16_t*)w;     w += (long)IC * C * 2;
  bf16_t* Wwb = (bf16_t*)w;     w += (long)C * IC * 2;
  bf16_t* fm = (bf16_t*)w;      w += (long)N * N * 2;   // f*mask logits -> P
  bf16_t* y16 = (bf16_t*)w;     w += (long)N * IC * 2;
  float* mrowb = (float*)w;     w += (long)N * 4;       // mask-softmax max
  float* invrowb = (float*)w;   w += (long)N * 4;       // mask-softmax 1/sum

  cast_f32_bf16_k<<<8192, 256, 0, stream>>>(x, xb, (long)N * C / 8);
  cast_f32_bf16_k<<<8192, 256, 0, stream>>>(mask_w, mwb, (long)N * C / 8);
  cast_f32_bf16_k<<<1024, 256, 0, stream>>>(theta_w, thwb, (long)IC * C / 8);
  cast_f32_bf16_k<<<1024, 256, 0, stream>>>(phi_w, phwb, (long)IC * C / 8);
  cast_f32_bf16_k<<<1024, 256, 0, stream>>>(g_w, gwb, (long)IC * C / 8);
  cast_f32_bf16_k<<<1024, 256, 0, stream>>>(W_w, Wwb, (long)C * IC / 8);

  // projections (128^2 kernel, XCD-grouped)
  gemm_nt<1, false, false, true, 0><<<dim3(IC / 128, N / 128), 256, 0, stream>>>(
      xb, thwb, theta_b, nullptr, nullptr, nullptr, th16, N, IC, C);
  gemm_nt<1, false, false, true, 0><<<dim3(IC / 128, N / 128), 256, 0, stream>>>(
      xb, phwb, phi_b, nullptr, nullptr, nullptr, ph16, N, IC, C);
  gemm_nt<2, false, false, true, 1><<<dim3(N / 128, IC / 128), 256, 0, stream>>>(
      gwb, xb, g_b, nullptr, nullptr, nullptr, gT16, IC, N, C);
  // mask logits (8-phase 256^2 kernel), bias per col -> raw ML
  gemm256p<1, false><<<dim3(N / 256, N / 256), 512, 0, stream>>>(
      xb, mwb, mask_b, nullptr, nullptr, nullptr, ML, N, N, C);
  // mask softmax stats only (read-only pass)
  softmax_stats<<<N, 256, 0, stream>>>(ML, mrowb, invrowb);
  // f*mask logits (8-phase 256^2 kernel) with folded exp-mask epilogue
  gemm256p<0, true><<<dim3(N / 256, N / 256), 512, 0, stream>>>(
      th16, ph16, nullptr, ML, mrowb, invrowb, fm, N, N, IC);
  softmax_f_k<<<N, 256, 0, stream>>>(fm, f_out);
  // y = P @ g_x (NT via gT16), XCD-grouped on A rows
  gemm_nt<0, false, false, true, 0><<<dim3(IC / 128, N / 128), 256, 0, stream>>>(
      fm, gT16, nullptr, nullptr, nullptr, nullptr, y16, N, IC, N);
  // z = y @ W_w^T + W_b + x
  gemm_nt<1, false, true, false, 0><<<dim3(C / 128, N / 128), 256, 0, stream>>>(
      y16, Wwb, W_b, nullptr, x, z_out, nullptr, N, C, IC);
}

// Round 12
// 1010.039 us; speedup vs baseline: 4.8132x; 1.0679x over previous
//
#include <hip/hip_runtime.h>
#include <hip/hip_bf16.h>

typedef __bf16 bf16_t;
typedef __bf16 bf16x8 __attribute__((ext_vector_type(8)));
typedef float f32x4 __attribute__((ext_vector_type(4)));

#define GLOAD16(gp, lp) __builtin_amdgcn_global_load_lds(                      \
    (const __attribute__((address_space(1))) void*)(gp),                       \
    (__attribute__((address_space(3))) void*)(lp), 16, 0, 0)
#define BARRIER() asm volatile("s_barrier" ::: "memory")
#define VMC(n) asm volatile("s_waitcnt vmcnt(" #n ")" ::: "memory")
#define LGK0()                                                                 \
  do {                                                                         \
    asm volatile("s_waitcnt lgkmcnt(0)" ::: "memory");                         \
    __builtin_amdgcn_sched_barrier(0);                                         \
  } while (0)

// ---------------- cast fp32 -> bf16 (vectorized x8) ----------------
__global__ __launch_bounds__(256) void cast_f32_bf16_k(
    const float* __restrict__ in, bf16_t* __restrict__ out, long n8) {
  long i = (long)blockIdx.x * blockDim.x + threadIdx.x;
  long stride = (long)gridDim.x * blockDim.x;
  for (; i < n8; i += stride) {
    long e = i * 8;
    float4 a = *(const float4*)(in + e);
    float4 b = *(const float4*)(in + e + 4);
    bf16x8 o;
    o[0] = (__bf16)a.x; o[1] = (__bf16)a.y; o[2] = (__bf16)a.z; o[3] = (__bf16)a.w;
    o[4] = (__bf16)b.x; o[5] = (__bf16)b.y; o[6] = (__bf16)b.z; o[7] = (__bf16)b.w;
    *(bf16x8*)(out + e) = o;
  }
}

// ============ 256x256-tile 8-wave GEMM, BK=64, 1 barrier / 1 vmcnt per
// K-tile (round-8 measured-best body). 4 quadrant-phases: same-phase lgkm(0),
// no mid-tile barriers. LDS: 2 x 64KB buffers {A 256x128B, B 256x128B}.
// 16B slot ^= (row&7); staging inverse-swizzles the global source (linear
// LDS dest). A/B have independent row strides lda/ldb (elements).
// Epilogue: BIAS(col), EMASK (fold mask softmax: *= exp(ml-mrow)*invrow),
// RES (+= res), OUTBF16 or fp32.
template <int BIAS, bool EMASK, bool RES, bool OUTBF16>
__global__ __launch_bounds__(512, 2) void gemm256(
    const bf16_t* __restrict__ A, long lda, const bf16_t* __restrict__ B,
    long ldb, const float* __restrict__ bias, const bf16_t* __restrict__ ml,
    const float* __restrict__ mrow, const float* __restrict__ invrow,
    const float* __restrict__ res, float* __restrict__ outf,
    bf16_t* __restrict__ outb, int M, int N, int K) {
  __shared__ __align__(1024) char lds[131072];
  const int tid = threadIdx.x;
  const int gx = N >> 8;
  int bid = blockIdx.y * gx + blockIdx.x;
  const int nwg = gridDim.x * gridDim.y;  // multiple of 8 for our shapes
  const int cpx = nwg >> 3;
  bid = (bid & 7) * cpx + (bid >> 3);     // XCD-aware bijective swizzle
  const long row0 = (long)(bid / gx) * 256;
  const long col0 = (long)(bid % gx) * 256;

  const int w = tid >> 6, lane = tid & 63;
  const int wm = w >> 2, wn = w & 3;      // 2M x 4N waves
  const int fr = lane & 15, fq = lane >> 4;

  // read-side bases: row stride 128B; slot(kk,fq) ^= fr&7
  const int arow = (wm * 128 + fr) * 128;           // A region byte base
  const int brow = 32768 + (wn * 64 + fr) * 128;    // B region byte base
  const int sw0 = ((fq ^ (fr & 7)) << 4);           // kk=0
  const int sw1 = (((4 | fq) ^ (fr & 7)) << 4);     // kk=1

  // staging: thread covers phys bytes tid*16 and tid*16+8192 of each 16KB
  // half-tile; row r0 = tid>>3 (second load +64 rows); source k-chunk
  // inverse-swizzled: s0 = (tid&7) ^ (r0&7).
  const int r0 = tid >> 3;
  const int s0 = (tid & 7) ^ (r0 & 7);
  const bf16_t* Ap = A + (row0 + r0) * lda + s0 * 8;
  const bf16_t* Bp = B + (col0 + r0) * ldb + s0 * 8;
  const int dstA = w * 1024;  // + lane*16 implicit in global_load_lds

#define STG_A(h, U)                                                            \
  {                                                                            \
    const bf16_t* s_ = Ap + (long)(h)*128 * lda + (long)(U)*64;                \
    char* d_ = lds + (((U)&1) * 65536) + (h)*16384 + dstA;                     \
    GLOAD16(s_, d_);                                                           \
    GLOAD16(s_ + 64 * lda, d_ + 8192);                                         \
  }
#define STG_B(h, U)                                                            \
  {                                                                            \
    const bf16_t* s_ = Bp + (long)(h)*128 * ldb + (long)(U)*64;                \
    char* d_ = lds + (((U)&1) * 65536) + 32768 + (h)*16384 + dstA;             \
    GLOAD16(s_, d_);                                                           \
    GLOAD16(s_ + 64 * ldb, d_ + 8192);                                         \
  }
// A-subtile s (4 i-frags x 2 kk = 8 b128) into aS
#define RD_A(buf, s)                                                           \
  {                                                                            \
    _Pragma("unroll") for (int i = 0; i < 4; ++i) {                            \
      aS[i * 2] = *(const bf16x8*)((buf) + arow + ((s)*4 + i) * 2048 + sw0);   \
      aS[i * 2 + 1] =                                                          \
          *(const bf16x8*)((buf) + arow + ((s)*4 + i) * 2048 + sw1);           \
    }                                                                          \
  }
// B-subtile s (2 j-frags x 2 kk = 4 b128) into dst
#define RD_B(dst, buf, s)                                                      \
  {                                                                            \
    _Pragma("unroll") for (int j = 0; j < 2; ++j) {                            \
      dst[j * 2] = *(const bf16x8*)((buf) + brow + ((s)*2 + j) * 2048 + sw0);  \
      dst[j * 2 + 1] =                                                         \
          *(const bf16x8*)((buf) + brow + ((s)*2 + j) * 2048 + sw1);           \
    }                                                                          \
  }
#define QUAD(BV, I0, J0)                                                       \
  {                                                                            \
    __builtin_amdgcn_s_setprio(1);                                             \
    _Pragma("unroll") for (int i = 0; i < 4; ++i)                              \
        _Pragma("unroll") for (int j = 0; j < 2; ++j)                          \
            _Pragma("unroll") for (int kk = 0; kk < 2; ++kk)                   \
                acc[I0 + i][J0 + j] = __builtin_amdgcn_mfma_f32_16x16x32_bf16( \
                    aS[i * 2 + kk], BV[j * 2 + kk], acc[I0 + i][J0 + j], 0, 0, \
                    0);                                                        \
    __builtin_amdgcn_s_setprio(0);                                             \
  }

  f32x4 acc[8][4] = {};
  bf16x8 aS[8], bA[4], bB[4];
  const int NT = K >> 6;  // >= 2

  // prologue: stage tile 0 into buf0
  STG_A(0, 0); STG_A(1, 0); STG_B(0, 0); STG_B(1, 0);

  for (int T = 0; T < NT; ++T) {
    char* buf = lds + (T & 1) * 65536;
    const bool ST = (T < NT - 1);
    // ph0: tile-T buffer ready (all waves) -> read A0,B0; stage A0(T+1)
    VMC(0);
    BARRIER();
    if (ST) STG_A(0, T + 1);
    RD_A(buf, 0);
    RD_B(bA, buf, 0);
    LGK0();
    QUAD(bA, 0, 0);
    // ph1: read B1; stage A1(T+1)
    RD_B(bB, buf, 1);
    if (ST) STG_A(1, T + 1);
    LGK0();
    QUAD(bB, 0, 2);
    // ph2: read A1; stage B0(T+1)
    RD_A(buf, 1);
    if (ST) STG_B(0, T + 1);
    LGK0();
    QUAD(bB, 4, 2);
    // ph3: stage B1(T+1); B0 frags still live
    if (ST) STG_B(1, T + 1);
    QUAD(bA, 4, 0);
  }
#undef STG_A
#undef STG_B
#undef RD_A
#undef RD_B
#undef QUAD

  // epilogue: C/D layout col=lane&15, row=(lane>>4)*4+r
#pragma unroll
  for (int i = 0; i < 8; ++i)
#pragma unroll
    for (int j = 0; j < 4; ++j)
#pragma unroll
      for (int r = 0; r < 4; ++r) {
        long gi = row0 + wm * 128 + i * 16 + fq * 4 + r;
        long gj = col0 + wn * 64 + j * 16 + fr;
        float v = acc[i][j][r];
        if (BIAS == 1) v += bias[gj];
        long idx = gi * (long)N + gj;
        if (EMASK) v *= __expf((float)ml[idx] - mrow[gi]) * invrow[gi];
        if (RES) v += res[idx];
        if (OUTBF16) outb[idx] = (bf16_t)v;
        else outf[idx] = v;
      }
}

// ---------------- NT GEMM (m97 128x128), slot-swizzled, XCD-grouped --------
// GROUP 0: blocks sharing an A row-tile grouped on one XCD (requires gy%8==0)
// GROUP 1: blocks sharing a B col-tile grouped on one XCD (requires gx%8==0)
template <int BIAS, bool MUL, bool RES, bool OUTBF16, int GROUP>
__global__ __launch_bounds__(256) void gemm_nt(
    const bf16_t* __restrict__ A, const bf16_t* __restrict__ B,
    const float* __restrict__ bias, const bf16_t* __restrict__ mulm,
    const float* __restrict__ res, float* __restrict__ outf,
    bf16_t* __restrict__ outb, int M, int N, int K) {
  __shared__ bf16_t As[128 * 32];
  __shared__ bf16_t Bs[128 * 32];
  const int tid = threadIdx.x;
  const int gx = gridDim.x, gy = gridDim.y;
  const int n = blockIdx.y * gx + blockIdx.x;
  const int xcd = n & 7, q = n >> 3;
  int br, bc;
  if (GROUP == 0) { br = xcd + 8 * (q / gx); bc = q % gx; }
  else            { bc = xcd + 8 * (q / gy); br = q % gy; }
  const long row0 = (long)br * 128;
  const long col0 = (long)bc * 128;
  const int wid = tid >> 6, lane = tid & 63;
  const int wr = (wid >> 1) * 64;
  const int wc = (wid & 1) * 64;
  const int fr = lane & 15, fq = lane >> 4;
  const int sx = (fr >> 1) & 3;
  const int srow = tid >> 2;
  const int scol = ((tid & 3) ^ ((srow >> 1) & 3)) * 8;  // inverse-swz source

  f32x4 acc[4][4] = {};

  const bf16_t* Ag = A + (row0 + srow) * (long)K + scol;
  const bf16_t* Bg = B + (col0 + srow) * (long)K + scol;
  const long k64 = 64L * K;
  bf16_t* ldsA = As + wid * 512;
  bf16_t* ldsB = Bs + wid * 512;

  for (int k0 = 0; k0 < K; k0 += 32) {
    GLOAD16(Ag + k0, ldsA);
    GLOAD16(Ag + k0 + k64, ldsA + 2048);
    GLOAD16(Bg + k0, ldsB);
    GLOAD16(Bg + k0 + k64, ldsB + 2048);
    __syncthreads();
    bf16x8 av[4], bv[4];
#pragma unroll
    for (int i = 0; i < 4; i++)
      av[i] = *(const bf16x8*)(As + (wr + i * 16 + fr) * 32 + ((fq ^ sx) << 3));
#pragma unroll
    for (int j = 0; j < 4; j++)
      bv[j] = *(const bf16x8*)(Bs + (wc + j * 16 + fr) * 32 + ((fq ^ sx) << 3));
#pragma unroll
    for (int i = 0; i < 4; i++)
#pragma unroll
      for (int j = 0; j < 4; j++)
        acc[i][j] = __builtin_amdgcn_mfma_f32_16x16x32_bf16(av[i], bv[j],
                                                            acc[i][j], 0, 0, 0);
    __syncthreads();
  }

#pragma unroll
  for (int i = 0; i < 4; i++) {
#pragma unroll
    for (int j = 0; j < 4; j++) {
#pragma unroll
      for (int r = 0; r < 4; r++) {
        long gi = row0 + wr + i * 16 + fq * 4 + r;
        long gj = col0 + wc + j * 16 + fr;
        float v = acc[i][j][r];
        if (BIAS == 1) v += bias[gj];
        if (BIAS == 2) v += bias[gi];
        long idx = gi * (long)N + gj;
        if (MUL) v *= (float)mulm[idx];
        if (RES) v += res[idx];
        if (OUTBF16) outb[idx] = (bf16_t)v;
        else outf[idx] = v;
      }
    }
  }
}

// ------- row softmax stats over 8192 cols: write per-row max and 1/sum ----
__global__ __launch_bounds__(256) void softmax_stats(
    const bf16_t* __restrict__ buf, float* __restrict__ mrow,
    float* __restrict__ invrow) {
  const long row = blockIdx.x;
  const bf16_t* p = buf + row * 8192;
  const int t = threadIdx.x;
  float v[32];
#pragma unroll
  for (int i = 0; i < 4; i++) {
    bf16x8 raw = *(const bf16x8*)(p + t * 32 + i * 8);
#pragma unroll
    for (int j = 0; j < 8; j++) v[i * 8 + j] = (float)raw[j];
  }
  float m = -1e30f;
#pragma unroll
  for (int i = 0; i < 32; i++) m = fmaxf(m, v[i]);
  for (int off = 32; off; off >>= 1) m = fmaxf(m, __shfl_xor(m, off, 64));
  __shared__ float redm[4], reds[4];
  if ((t & 63) == 0) redm[t >> 6] = m;
  __syncthreads();
  m = fmaxf(fmaxf(redm[0], redm[1]), fmaxf(redm[2], redm[3]));
  float s = 0.f;
#pragma unroll
  for (int i = 0; i < 32; i++) s += __expf(v[i] - m);
  for (int off = 32; off; off >>= 1) s += __shfl_xor(s, off, 64);
  if ((t & 63) == 0) reds[t >> 6] = s;
  __syncthreads();
  if (t == 0) {
    s = reds[0] + reds[1] + reds[2] + reds[3];
    mrow[row] = m;
    invrow[row] = 1.0f / s;
  }
}

// --------- row softmax: bf16 logits in, fp32 out + bf16 in-place ----------
__global__ __launch_bounds__(256) void softmax_f_k(bf16_t* __restrict__ fm,
                                                   float* __restrict__ outf) {
  const long row = blockIdx.x;
  bf16_t* p = fm + row * 8192;
  float* q = outf + row * 8192;
  const int t = threadIdx.x;
  float v[32];
#pragma unroll
  for (int i = 0; i < 4; i++) {
    bf16x8 raw = *(const bf16x8*)(p + t * 32 + i * 8);
#pragma unroll
    for (int j = 0; j < 8; j++) v[i * 8 + j] = (float)raw[j];
  }
  float m = -1e30f;
#pragma unroll
  for (int i = 0; i < 32; i++) m = fmaxf(m, v[i]);
  for (int off = 32; off; off >>= 1) m = fmaxf(m, __shfl_xor(m, off, 64));
  __shared__ float redm[4], reds[4];
  if ((t & 63) == 0) redm[t >> 6] = m;
  __syncthreads();
  m = fmaxf(fmaxf(redm[0], redm[1]), fmaxf(redm[2], redm[3]));
  float s = 0.f;
#pragma unroll
  for (int i = 0; i < 32; i++) {
    v[i] = __expf(v[i] - m);
    s += v[i];
  }
  for (int off = 32; off; off >>= 1) s += __shfl_xor(s, off, 64);
  if ((t & 63) == 0) reds[t >> 6] = s;
  __syncthreads();
  s = reds[0] + reds[1] + reds[2] + reds[3];
  float inv = 1.0f / s;
#pragma unroll
  for (int i = 0; i < 8; i++) {
    float4 o;
    o.x = v[i * 4 + 0] * inv;
    o.y = v[i * 4 + 1] * inv;
    o.z = v[i * 4 + 2] * inv;
    o.w = v[i * 4 + 3] * inv;
    *(float4*)(q + t * 32 + i * 4) = o;
  }
#pragma unroll
  for (int i = 0; i < 4; i++) {
    bf16x8 o;
#pragma unroll
    for (int j = 0; j < 8; j++) o[j] = (bf16_t)(v[i * 8 + j] * inv);
    *(bf16x8*)(p + t * 32 + i * 8) = o;
  }
}

// ---------------------------------------------------------------------------
extern "C" void kernel_launch(void* const* d_in, const int* in_sizes, int n_in,
                              void* d_out, int out_size, void* d_ws,
                              size_t ws_size, hipStream_t stream) {
  const int N = 8192, C = 2048, IC = 1024;
  const float* x = (const float*)d_in[0];
  const float* theta_w = (const float*)d_in[1];
  const float* theta_b = (const float*)d_in[2];
  const float* phi_w = (const float*)d_in[3];
  const float* phi_b = (const float*)d_in[4];
  const float* g_w = (const float*)d_in[5];
  const float* g_b = (const float*)d_in[6];
  const float* W_w = (const float*)d_in[7];
  const float* W_b = (const float*)d_in[8];
  const float* mask_w = (const float*)d_in[9];
  const float* mask_b = (const float*)d_in[10];

  float* z_out = (float*)d_out;            // [N,C] fp32
  float* f_out = z_out + (long)N * C;      // [N,N] fp32

  // d_out-hosted scratch (dead before those regions' final writes):
  bf16_t* ML = (bf16_t*)f_out;             // [N,N] bf16 raw mask logits
  bf16_t* thph16 = (bf16_t*)z_out;         // [N,2048]: theta cols 0-1023, phi 1024-2047
  bf16_t* gT16 = thph16 + (long)N * 2048;  // [IC,N]  (48MB total <= 64MB region)

  char* w = (char*)d_ws;
  bf16_t* xb = (bf16_t*)w;      w += (long)N * C * 2;
  bf16_t* mwb = (bf16_t*)w;     w += (long)N * C * 2;
  bf16_t* thwb = (bf16_t*)w;    w += (long)IC * C * 2;  // theta_w bf16
  bf16_t* phwb = (bf16_t*)w;    w += (long)IC * C * 2;  // phi_w bf16 (contiguous after thwb!)
  bf16_t* gwb = (bf16_t*)w;     w += (long)IC * C * 2;
  bf16_t* Wwb = (bf16_t*)w;     w += (long)C * IC * 2;
  bf16_t* fm = (bf16_t*)w;      w += (long)N * N * 2;   // f*mask logits -> P
  bf16_t* y16 = (bf16_t*)w;     w += (long)N * IC * 2;
  float* mrowb = (float*)w;     w += (long)N * 4;       // mask-softmax max
  float* invrowb = (float*)w;   w += (long)N * 4;       // mask-softmax 1/sum
  float* thph_b = (float*)w;    w += (long)2 * IC * 4;  // concat theta_b||phi_b

  cast_f32_bf16_k<<<8192, 256, 0, stream>>>(x, xb, (long)N * C / 8);
  cast_f32_bf16_k<<<8192, 256, 0, stream>>>(mask_w, mwb, (long)N * C / 8);
  cast_f32_bf16_k<<<1024, 256, 0, stream>>>(theta_w, thwb, (long)IC * C / 8);
  cast_f32_bf16_k<<<1024, 256, 0, stream>>>(phi_w, phwb, (long)IC * C / 8);
  cast_f32_bf16_k<<<1024, 256, 0, stream>>>(g_w, gwb, (long)IC * C / 8);
  cast_f32_bf16_k<<<1024, 256, 0, stream>>>(W_w, Wwb, (long)C * IC / 8);
  hipMemcpyAsync(thph_b, theta_b, IC * 4, hipMemcpyDeviceToDevice, stream);
  hipMemcpyAsync(thph_b + IC, phi_b, IC * 4, hipMemcpyDeviceToDevice, stream);

  // theta+phi merged projection: [8192,2048] = xb @ [thwb;phwb]^T + bias
  gemm256<1, false, false, true><<<dim3(2048 / 256, N / 256), 512, 0, stream>>>(
      xb, C, thwb, C, thph_b, nullptr, nullptr, nullptr, nullptr, nullptr,
      thph16, N, 2048, C);
  // g_x^T : [IC,N] (128^2 kernel, XCD-grouped on B cols)
  gemm_nt<2, false, false, true, 1><<<dim3(N / 128, IC / 128), 256, 0, stream>>>(
      gwb, xb, g_b, nullptr, nullptr, nullptr, gT16, IC, N, C);
  // mask logits -> raw ML (bias per col)
  gemm256<1, false, false, true><<<dim3(N / 256, N / 256), 512, 0, stream>>>(
      xb, C, mwb, C, mask_b, nullptr, nullptr, nullptr, nullptr, nullptr,
      ML, N, N, C);
  // mask softmax stats only (read-only pass)
  softmax_stats<<<N, 256, 0, stream>>>(ML, mrowb, invrowb);
  // f*mask logits: theta_x @ phi_x^T with folded exp-mask epilogue
  gemm256<0, true, false, true><<<dim3(N / 256, N / 256), 512, 0, stream>>>(
      thph16, 2048, thph16 + 1024, 2048, nullptr, ML, mrowb, invrowb,
      nullptr, nullptr, fm, N, N, IC);
  softmax_f_k<<<N, 256, 0, stream>>>(fm, f_out);
  // y = P @ g_x (NT via gT16), XCD-grouped on A rows
  gemm_nt<0, false, false, true, 0><<<dim3(IC / 128, N / 128), 256, 0, stream>>>(
      fm, gT16, nullptr, nullptr, nullptr, nullptr, y16, N, IC, N);
  // z = y @ W_w^T + W_b + x (256^2 kernel, fp32 out + residual)
  gemm256<1, false, true, false><<<dim3(C / 256, N / 256), 512, 0, stream>>>(
      y16, IC, Wwb, IC, W_b, nullptr, nullptr, nullptr, x, z_out, nullptr,
      N, C, IC);
}

// Round 13
// 954.050 us; speedup vs baseline: 5.0957x; 1.0587x over previous
//
#include <hip/hip_runtime.h>
#include <hip/hip_bf16.h>

typedef __bf16 bf16_t;
typedef __bf16 bf16x8 __attribute__((ext_vector_type(8)));
typedef float f32x4 __attribute__((ext_vector_type(4)));

#define GLOAD16(gp, lp) __builtin_amdgcn_global_load_lds(                      \
    (const __attribute__((address_space(1))) void*)(gp),                       \
    (__attribute__((address_space(3))) void*)(lp), 16, 0, 0)
#define BARRIER() asm volatile("s_barrier" ::: "memory")
#define VMC(n) asm volatile("s_waitcnt vmcnt(" #n ")" ::: "memory")
#define LGK0()                                                                 \
  do {                                                                         \
    asm volatile("s_waitcnt lgkmcnt(0)" ::: "memory");                         \
    __builtin_amdgcn_sched_barrier(0);                                         \
  } while (0)

// -------- fused fp32 -> bf16 casts (6 segments, one launch) --------
__global__ __launch_bounds__(256) void cast_all_k(
    const float* __restrict__ x, bf16_t* __restrict__ xb,
    const float* __restrict__ mw, bf16_t* __restrict__ mwb,
    const float* __restrict__ tw, bf16_t* __restrict__ twb,
    const float* __restrict__ pw, bf16_t* __restrict__ pwb,
    const float* __restrict__ gw, bf16_t* __restrict__ gwb,
    const float* __restrict__ Ww, bf16_t* __restrict__ Wwb) {
  const long NB = 2097152;   // 8192*2048/8
  const long WB = 262144;    // 1024*2048/8
  const long total = 2 * NB + 4 * WB;
  long i = (long)blockIdx.x * blockDim.x + threadIdx.x;
  long stride = (long)gridDim.x * blockDim.x;
  for (; i < total; i += stride) {
    const float* src;
    bf16_t* dst;
    long off;
    if (i < NB) {
      src = x; dst = xb; off = i;
    } else if (i < 2 * NB) {
      src = mw; dst = mwb; off = i - NB;
    } else {
      long j = i - 2 * NB;
      int seg = (int)(j >> 18);
      off = j & (WB - 1);
      src = (seg == 0) ? tw : (seg == 1) ? pw : (seg == 2) ? gw : Ww;
      dst = (seg == 0) ? twb : (seg == 1) ? pwb : (seg == 2) ? gwb : Wwb;
    }
    long e = off * 8;
    float4 a = *(const float4*)(src + e);
    float4 b = *(const float4*)(src + e + 4);
    bf16x8 o;
    o[0] = (__bf16)a.x; o[1] = (__bf16)a.y; o[2] = (__bf16)a.z; o[3] = (__bf16)a.w;
    o[4] = (__bf16)b.x; o[5] = (__bf16)b.y; o[6] = (__bf16)b.z; o[7] = (__bf16)b.w;
    *(bf16x8*)(dst + e) = o;
  }
}

// ============ 256x256-tile 8-wave GEMM, BK=64, 1 barrier / 1 vmcnt per
// K-tile (round-8 measured-best body). 4 quadrant-phases: same-phase lgkm(0),
// no mid-tile barriers. LDS: 2 x 64KB buffers {A 256x128B, B 256x128B}.
// 16B slot ^= (row&7); staging inverse-swizzles the global source (linear
// LDS dest). A/B have independent row strides lda/ldb (elements).
template <int BIAS, bool EMASK, bool RES, bool OUTBF16>
__global__ __launch_bounds__(512, 2) void gemm256(
    const bf16_t* __restrict__ A, long lda, const bf16_t* __restrict__ B,
    long ldb, const float* __restrict__ bias, const bf16_t* __restrict__ ml,
    const float* __restrict__ mrow, const float* __restrict__ invrow,
    const float* __restrict__ res, float* __restrict__ outf,
    bf16_t* __restrict__ outb, int M, int N, int K) {
  __shared__ __align__(1024) char lds[131072];
  const int tid = threadIdx.x;
  const int gx = N >> 8;
  int bid = blockIdx.y * gx + blockIdx.x;
  const int nwg = gridDim.x * gridDim.y;  // multiple of 8 for our shapes
  const int cpx = nwg >> 3;
  bid = (bid & 7) * cpx + (bid >> 3);     // XCD-aware bijective swizzle
  const long row0 = (long)(bid / gx) * 256;
  const long col0 = (long)(bid % gx) * 256;

  const int w = tid >> 6, lane = tid & 63;
  const int wm = w >> 2, wn = w & 3;      // 2M x 4N waves
  const int fr = lane & 15, fq = lane >> 4;

  const int arow = (wm * 128 + fr) * 128;
  const int brow = 32768 + (wn * 64 + fr) * 128;
  const int sw0 = ((fq ^ (fr & 7)) << 4);
  const int sw1 = (((4 | fq) ^ (fr & 7)) << 4);

  const int r0 = tid >> 3;
  const int s0 = (tid & 7) ^ (r0 & 7);
  const bf16_t* Ap = A + (row0 + r0) * lda + s0 * 8;
  const bf16_t* Bp = B + (col0 + r0) * ldb + s0 * 8;
  const int dstA = w * 1024;

#define STG_A(h, U)                                                            \
  {                                                                            \
    const bf16_t* s_ = Ap + (long)(h)*128 * lda + (long)(U)*64;                \
    char* d_ = lds + (((U)&1) * 65536) + (h)*16384 + dstA;                     \
    GLOAD16(s_, d_);                                                           \
    GLOAD16(s_ + 64 * lda, d_ + 8192);                                         \
  }
#define STG_B(h, U)                                                            \
  {                                                                            \
    const bf16_t* s_ = Bp + (long)(h)*128 * ldb + (long)(U)*64;                \
    char* d_ = lds + (((U)&1) * 65536) + 32768 + (h)*16384 + dstA;             \
    GLOAD16(s_, d_);                                                           \
    GLOAD16(s_ + 64 * ldb, d_ + 8192);                                         \
  }
#define RD_A(buf, s)                                                           \
  {                                                                            \
    _Pragma("unroll") for (int i = 0; i < 4; ++i) {                            \
      aS[i * 2] = *(const bf16x8*)((buf) + arow + ((s)*4 + i) * 2048 + sw0);   \
      aS[i * 2 + 1] =                                                          \
          *(const bf16x8*)((buf) + arow + ((s)*4 + i) * 2048 + sw1);           \
    }                                                                          \
  }
#define RD_B(dst, buf, s)                                                      \
  {                                                                            \
    _Pragma("unroll") for (int j = 0; j < 2; ++j) {                            \
      dst[j * 2] = *(const bf16x8*)((buf) + brow + ((s)*2 + j) * 2048 + sw0);  \
      dst[j * 2 + 1] =                                                         \
          *(const bf16x8*)((buf) + brow + ((s)*2 + j) * 2048 + sw1);           \
    }                                                                          \
  }
#define QUAD(BV, I0, J0)                                                       \
  {                                                                            \
    __builtin_amdgcn_s_setprio(1);                                             \
    _Pragma("unroll") for (int i = 0; i < 4; ++i)                              \
        _Pragma("unroll") for (int j = 0; j < 2; ++j)                          \
            _Pragma("unroll") for (int kk = 0; kk < 2; ++kk)                   \
                acc[I0 + i][J0 + j] = __builtin_amdgcn_mfma_f32_16x16x32_bf16( \
                    aS[i * 2 + kk], BV[j * 2 + kk], acc[I0 + i][J0 + j], 0, 0, \
                    0);                                                        \
    __builtin_amdgcn_s_setprio(0);                                             \
  }

  f32x4 acc[8][4] = {};
  bf16x8 aS[8], bA[4], bB[4];
  const int NT = K >> 6;  // >= 2

  STG_A(0, 0); STG_A(1, 0); STG_B(0, 0); STG_B(1, 0);

  for (int T = 0; T < NT; ++T) {
    char* buf = lds + (T & 1) * 65536;
    const bool ST = (T < NT - 1);
    VMC(0);
    BARRIER();
    if (ST) STG_A(0, T + 1);
    RD_A(buf, 0);
    RD_B(bA, buf, 0);
    LGK0();
    QUAD(bA, 0, 0);
    RD_B(bB, buf, 1);
    if (ST) STG_A(1, T + 1);
    LGK0();
    QUAD(bB, 0, 2);
    RD_A(buf, 1);
    if (ST) STG_B(0, T + 1);
    LGK0();
    QUAD(bB, 4, 2);
    if (ST) STG_B(1, T + 1);
    QUAD(bA, 4, 0);
  }
#undef STG_A
#undef STG_B
#undef RD_A
#undef RD_B
#undef QUAD

#pragma unroll
  for (int i = 0; i < 8; ++i)
#pragma unroll
    for (int j = 0; j < 4; ++j)
#pragma unroll
      for (int r = 0; r < 4; ++r) {
        long gi = row0 + wm * 128 + i * 16 + fq * 4 + r;
        long gj = col0 + wn * 64 + j * 16 + fr;
        float v = acc[i][j][r];
        if (BIAS == 1) v += bias[gj];
        long idx = gi * (long)N + gj;
        if (EMASK) v *= __expf((float)ml[idx] - mrow[gi]) * invrow[gi];
        if (RES) v += res[idx];
        if (OUTBF16) outb[idx] = (bf16_t)v;
        else outf[idx] = v;
      }
}

// ============ 256-row x 128-col tile 8-wave GEMM, BK=64 (same body) ========
// For outputs with N a multiple of 128 only (y-GEMM). Grid (N/128, M/256).
// Waves: 4M x 2N, per-wave 64x64 out (acc 64 VGPR). LDS: 2 x 48KB
// {A 256x128B, B 128x128B}. Same swizzle/schedule as gemm256.
__global__ __launch_bounds__(512, 2) void gemmT128(
    const bf16_t* __restrict__ A, long lda, const bf16_t* __restrict__ B,
    long ldb, bf16_t* __restrict__ out, int M, int N, int K) {
  __shared__ __align__(1024) char lds[98304];
  const int tid = threadIdx.x;
  const int gx = N >> 7;
  int bid = blockIdx.y * gx + blockIdx.x;
  const int nwg = gridDim.x * gridDim.y;  // multiple of 8
  const int cpx = nwg >> 3;
  bid = (bid & 7) * cpx + (bid >> 3);     // XCD-aware bijective swizzle
  const long row0 = (long)(bid / gx) * 256;
  const long col0 = (long)(bid % gx) * 128;

  const int w = tid >> 6, lane = tid & 63;
  const int wm = w >> 1, wn = w & 1;      // 4M x 2N waves
  const int fr = lane & 15, fq = lane >> 4;

  const int arow = (wm * 64 + fr) * 128;
  const int brow = 32768 + (wn * 64 + fr) * 128;
  const int sw0 = ((fq ^ (fr & 7)) << 4);
  const int sw1 = (((4 | fq) ^ (fr & 7)) << 4);

  // staging: phys p = c*8192 + tid*16; row = c*64 + (tid>>3); slot = tid&7
  const int r0 = tid >> 3;
  const int s0 = (tid & 7) ^ (r0 & 7);
  const bf16_t* Ap = A + (row0 + r0) * lda + s0 * 8;
  const bf16_t* Bp = B + (col0 + r0) * ldb + s0 * 8;
  const int dstA = w * 1024;

#define STG_A(U)                                                               \
  {                                                                            \
    char* d_ = lds + (((U)&1) * 49152) + dstA;                                 \
    const bf16_t* s_ = Ap + (long)(U)*64;                                      \
    GLOAD16(s_, d_);                                                           \
    GLOAD16(s_ + 64 * lda, d_ + 8192);                                         \
    GLOAD16(s_ + 128 * lda, d_ + 16384);                                       \
    GLOAD16(s_ + 192 * lda, d_ + 24576);                                       \
  }
#define STG_B(U)                                                               \
  {                                                                            \
    char* d_ = lds + (((U)&1) * 49152) + 32768 + dstA;                         \
    const bf16_t* s_ = Bp + (long)(U)*64;                                      \
    GLOAD16(s_, d_);                                                           \
    GLOAD16(s_ + 64 * ldb, d_ + 8192);                                         \
  }
#define RD_A(buf)                                                              \
  {                                                                            \
    _Pragma("unroll") for (int i = 0; i < 4; ++i) {                            \
      aS[i * 2] = *(const bf16x8*)((buf) + arow + i * 2048 + sw0);             \
      aS[i * 2 + 1] = *(const bf16x8*)((buf) + arow + i * 2048 + sw1);         \
    }                                                                          \
  }
#define RD_B(dst, buf, s)                                                      \
  {                                                                            \
    _Pragma("unroll") for (int j = 0; j < 2; ++j) {                            \
      dst[j * 2] = *(const bf16x8*)((buf) + brow + ((s)*2 + j) * 2048 + sw0);  \
      dst[j * 2 + 1] =                                                         \
          *(const bf16x8*)((buf) + brow + ((s)*2 + j) * 2048 + sw1);           \
    }                                                                          \
  }
#define QUAD(BV, J0)                                                           \
  {                                                                            \
    __builtin_amdgcn_s_setprio(1);                                             \
    _Pragma("unroll") for (int i = 0; i < 4; ++i)                              \
        _Pragma("unroll") for (int j = 0; j < 2; ++j)                          \
            _Pragma("unroll") for (int kk = 0; kk < 2; ++kk)                   \
                acc[i][J0 + j] = __builtin_amdgcn_mfma_f32_16x16x32_bf16(      \
                    aS[i * 2 + kk], BV[j * 2 + kk], acc[i][J0 + j], 0, 0, 0);  \
    __builtin_amdgcn_s_setprio(0);                                             \
  }

  f32x4 acc[4][4] = {};
  bf16x8 aS[8], bA[4], bB[4];
  const int NT = K >> 6;  // >= 2

  STG_A(0); STG_B(0);

  for (int T = 0; T < NT; ++T) {
    char* buf = lds + (T & 1) * 49152;
    const bool ST = (T < NT - 1);
    VMC(0);
    BARRIER();
    if (ST) STG_A(T + 1);
    RD_A(buf);
    RD_B(bA, buf, 0);
    LGK0();
    QUAD(bA, 0);
    RD_B(bB, buf, 1);
    if (ST) STG_B(T + 1);
    LGK0();
    QUAD(bB, 2);
  }
#undef STG_A
#undef STG_B
#undef RD_A
#undef RD_B
#undef QUAD

#pragma unroll
  for (int i = 0; i < 4; ++i)
#pragma unroll
    for (int j = 0; j < 4; ++j)
#pragma unroll
      for (int r = 0; r < 4; ++r) {
        long gi = row0 + wm * 64 + i * 16 + fq * 4 + r;
        long gj = col0 + wn * 64 + j * 16 + fr;
        out[gi * (long)N + gj] = (bf16_t)acc[i][j][r];
      }
}

// ---------------- NT GEMM (m97 128x128), slot-swizzled, XCD-grouped --------
template <int BIAS, bool MUL, bool RES, bool OUTBF16, int GROUP>
__global__ __launch_bounds__(256) void gemm_nt(
    const bf16_t* __restrict__ A, const bf16_t* __restrict__ B,
    const float* __restrict__ bias, const bf16_t* __restrict__ mulm,
    const float* __restrict__ res, float* __restrict__ outf,
    bf16_t* __restrict__ outb, int M, int N, int K) {
  __shared__ bf16_t As[128 * 32];
  __shared__ bf16_t Bs[128 * 32];
  const int tid = threadIdx.x;
  const int gx = gridDim.x, gy = gridDim.y;
  const int n = blockIdx.y * gx + blockIdx.x;
  const int xcd = n & 7, q = n >> 3;
  int br, bc;
  if (GROUP == 0) { br = xcd + 8 * (q / gx); bc = q % gx; }
  else            { bc = xcd + 8 * (q / gy); br = q % gy; }
  const long row0 = (long)br * 128;
  const long col0 = (long)bc * 128;
  const int wid = tid >> 6, lane = tid & 63;
  const int wr = (wid >> 1) * 64;
  const int wc = (wid & 1) * 64;
  const int fr = lane & 15, fq = lane >> 4;
  const int sx = (fr >> 1) & 3;
  const int srow = tid >> 2;
  const int scol = ((tid & 3) ^ ((srow >> 1) & 3)) * 8;

  f32x4 acc[4][4] = {};

  const bf16_t* Ag = A + (row0 + srow) * (long)K + scol;
  const bf16_t* Bg = B + (col0 + srow) * (long)K + scol;
  const long k64 = 64L * K;
  bf16_t* ldsA = As + wid * 512;
  bf16_t* ldsB = Bs + wid * 512;

  for (int k0 = 0; k0 < K; k0 += 32) {
    GLOAD16(Ag + k0, ldsA);
    GLOAD16(Ag + k0 + k64, ldsA + 2048);
    GLOAD16(Bg + k0, ldsB);
    GLOAD16(Bg + k0 + k64, ldsB + 2048);
    __syncthreads();
    bf16x8 av[4], bv[4];
#pragma unroll
    for (int i = 0; i < 4; i++)
      av[i] = *(const bf16x8*)(As + (wr + i * 16 + fr) * 32 + ((fq ^ sx) << 3));
#pragma unroll
    for (int j = 0; j < 4; j++)
      bv[j] = *(const bf16x8*)(Bs + (wc + j * 16 + fr) * 32 + ((fq ^ sx) << 3));
#pragma unroll
    for (int i = 0; i < 4; i++)
#pragma unroll
      for (int j = 0; j < 4; j++)
        acc[i][j] = __builtin_amdgcn_mfma_f32_16x16x32_bf16(av[i], bv[j],
                                                            acc[i][j], 0, 0, 0);
    __syncthreads();
  }

#pragma unroll
  for (int i = 0; i < 4; i++) {
#pragma unroll
    for (int j = 0; j < 4; j++) {
#pragma unroll
      for (int r = 0; r < 4; r++) {
        long gi = row0 + wr + i * 16 + fq * 4 + r;
        long gj = col0 + wc + j * 16 + fr;
        float v = acc[i][j][r];
        if (BIAS == 1) v += bias[gj];
        if (BIAS == 2) v += bias[gi];
        long idx = gi * (long)N + gj;
        if (MUL) v *= (float)mulm[idx];
        if (RES) v += res[idx];
        if (OUTBF16) outb[idx] = (bf16_t)v;
        else outf[idx] = v;
      }
    }
  }
}

// ------- row softmax stats over 8192 cols: write per-row max and 1/sum ----
__global__ __launch_bounds__(256) void softmax_stats(
    const bf16_t* __restrict__ buf, float* __restrict__ mrow,
    float* __restrict__ invrow) {
  const long row = blockIdx.x;
  const bf16_t* p = buf + row * 8192;
  const int t = threadIdx.x;
  float v[32];
#pragma unroll
  for (int i = 0; i < 4; i++) {
    bf16x8 raw = *(const bf16x8*)(p + t * 32 + i * 8);
#pragma unroll
    for (int j = 0; j < 8; j++) v[i * 8 + j] = (float)raw[j];
  }
  float m = -1e30f;
#pragma unroll
  for (int i = 0; i < 32; i++) m = fmaxf(m, v[i]);
  for (int off = 32; off; off >>= 1) m = fmaxf(m, __shfl_xor(m, off, 64));
  __shared__ float redm[4], reds[4];
  if ((t & 63) == 0) redm[t >> 6] = m;
  __syncthreads();
  m = fmaxf(fmaxf(redm[0], redm[1]), fmaxf(redm[2], redm[3]));
  float s = 0.f;
#pragma unroll
  for (int i = 0; i < 32; i++) s += __expf(v[i] - m);
  for (int off = 32; off; off >>= 1) s += __shfl_xor(s, off, 64);
  if ((t & 63) == 0) reds[t >> 6] = s;
  __syncthreads();
  if (t == 0) {
    s = reds[0] + reds[1] + reds[2] + reds[3];
    mrow[row] = m;
    invrow[row] = 1.0f / s;
  }
}

// --------- row softmax: bf16 logits in, fp32 out + bf16 in-place ----------
__global__ __launch_bounds__(256) void softmax_f_k(bf16_t* __restrict__ fm,
                                                   float* __restrict__ outf) {
  const long row = blockIdx.x;
  bf16_t* p = fm + row * 8192;
  float* q = outf + row * 8192;
  const int t = threadIdx.x;
  float v[32];
#pragma unroll
  for (int i = 0; i < 4; i++) {
    bf16x8 raw = *(const bf16x8*)(p + t * 32 + i * 8);
#pragma unroll
    for (int j = 0; j < 8; j++) v[i * 8 + j] = (float)raw[j];
  }
  float m = -1e30f;
#pragma unroll
  for (int i = 0; i < 32; i++) m = fmaxf(m, v[i]);
  for (int off = 32; off; off >>= 1) m = fmaxf(m, __shfl_xor(m, off, 64));
  __shared__ float redm[4], reds[4];
  if ((t & 63) == 0) redm[t >> 6] = m;
  __syncthreads();
  m = fmaxf(fmaxf(redm[0], redm[1]), fmaxf(redm[2], redm[3]));
  float s = 0.f;
#pragma unroll
  for (int i = 0; i < 32; i++) {
    v[i] = __expf(v[i] - m);
    s += v[i];
  }
  for (int off = 32; off; off >>= 1) s += __shfl_xor(s, off, 64);
  if ((t & 63) == 0) reds[t >> 6] = s;
  __syncthreads();
  s = reds[0] + reds[1] + reds[2] + reds[3];
  float inv = 1.0f / s;
#pragma unroll
  for (int i = 0; i < 8; i++) {
    float4 o;
    o.x = v[i * 4 + 0] * inv;
    o.y = v[i * 4 + 1] * inv;
    o.z = v[i * 4 + 2] * inv;
    o.w = v[i * 4 + 3] * inv;
    *(float4*)(q + t * 32 + i * 4) = o;
  }
#pragma unroll
  for (int i = 0; i < 4; i++) {
    bf16x8 o;
#pragma unroll
    for (int j = 0; j < 8; j++) o[j] = (bf16_t)(v[i * 8 + j] * inv);
    *(bf16x8*)(p + t * 32 + i * 8) = o;
  }
}

// ---------------------------------------------------------------------------
extern "C" void kernel_launch(void* const* d_in, const int* in_sizes, int n_in,
                              void* d_out, int out_size, void* d_ws,
                              size_t ws_size, hipStream_t stream) {
  const int N = 8192, C = 2048, IC = 1024;
  const float* x = (const float*)d_in[0];
  const float* theta_w = (const float*)d_in[1];
  const float* theta_b = (const float*)d_in[2];
  const float* phi_w = (const float*)d_in[3];
  const float* phi_b = (const float*)d_in[4];
  const float* g_w = (const float*)d_in[5];
  const float* g_b = (const float*)d_in[6];
  const float* W_w = (const float*)d_in[7];
  const float* W_b = (const float*)d_in[8];
  const float* mask_w = (const float*)d_in[9];
  const float* mask_b = (const float*)d_in[10];

  float* z_out = (float*)d_out;            // [N,C] fp32
  float* f_out = z_out + (long)N * C;      // [N,N] fp32

  bf16_t* ML = (bf16_t*)f_out;             // [N,N] bf16 raw mask logits
  bf16_t* thph16 = (bf16_t*)z_out;         // [N,2048]: theta | phi
  bf16_t* gT16 = thph16 + (long)N * 2048;  // [IC,N]

  char* w = (char*)d_ws;
  bf16_t* xb = (bf16_t*)w;      w += (long)N * C * 2;
  bf16_t* mwb = (bf16_t*)w;     w += (long)N * C * 2;
  bf16_t* thwb = (bf16_t*)w;    w += (long)IC * C * 2;
  bf16_t* phwb = (bf16_t*)w;    w += (long)IC * C * 2;
  bf16_t* gwb = (bf16_t*)w;     w += (long)IC * C * 2;
  bf16_t* Wwb = (bf16_t*)w;     w += (long)C * IC * 2;
  bf16_t* fm = (bf16_t*)w;      w += (long)N * N * 2;
  bf16_t* y16 = (bf16_t*)w;     w += (long)N * IC * 2;
  float* mrowb = (float*)w;     w += (long)N * 4;
  float* invrowb = (float*)w;   w += (long)N * 4;
  float* thph_b = (float*)w;    w += (long)2 * IC * 4;

  cast_all_k<<<4096, 256, 0, stream>>>(x, xb, mask_w, mwb, theta_w, thwb,
                                       phi_w, phwb, g_w, gwb, W_w, Wwb);
  hipMemcpyAsync(thph_b, theta_b, IC * 4, hipMemcpyDeviceToDevice, stream);
  hipMemcpyAsync(thph_b + IC, phi_b, IC * 4, hipMemcpyDeviceToDevice, stream);

  // theta+phi merged projection: [8192,2048] = xb @ [thwb;phwb]^T + bias
  gemm256<1, false, false, true><<<dim3(2048 / 256, N / 256), 512, 0, stream>>>(
      xb, C, thwb, C, thph_b, nullptr, nullptr, nullptr, nullptr, nullptr,
      thph16, N, 2048, C);
  // g_x^T : [IC,N] (128^2 kernel, XCD-grouped on B cols)
  gemm_nt<2, false, false, true, 1><<<dim3(N / 128, IC / 128), 256, 0, stream>>>(
      gwb, xb, g_b, nullptr, nullptr, nullptr, gT16, IC, N, C);
  // mask logits -> raw ML (bias per col)
  gemm256<1, false, false, true><<<dim3(N / 256, N / 256), 512, 0, stream>>>(
      xb, C, mwb, C, mask_b, nullptr, nullptr, nullptr, nullptr, nullptr,
      ML, N, N, C);
  // mask softmax stats only (read-only pass)
  softmax_stats<<<N, 256, 0, stream>>>(ML, mrowb, invrowb);
  // f*mask logits: theta_x @ phi_x^T with folded exp-mask epilogue
  gemm256<0, true, false, true><<<dim3(N / 256, N / 256), 512, 0, stream>>>(
      thph16, 2048, thph16 + 1024, 2048, nullptr, ML, mrowb, invrowb,
      nullptr, nullptr, fm, N, N, IC);
  softmax_f_k<<<N, 256, 0, stream>>>(fm, f_out);
  // y = P @ g_x (NT via gT16), 256x128-tile kernel, exact 256-block fill
  gemmT128<<<dim3(IC / 128, N / 256), 512, 0, stream>>>(
      fm, N, gT16, N, y16, N, IC, N);
  // z = y @ W_w^T + W_b + x (256^2 kernel, fp32 out + residual)
  gemm256<1, false, true, false><<<dim3(C / 256, N / 256), 512, 0, stream>>>(
      y16, IC, Wwb, IC, W_b, nullptr, nullptr, nullptr, x, z_out, nullptr,
      N, C, IC);
}